// Round 12
// baseline (318.545 us; speedup 1.0000x reference)
//
#include <hip/hip_runtime.h>
#include <hip/hip_bf16.h>
#include <math.h>

// GAT 2-layer forward for MI355X.
// R12 = R11 + (a) agg gather loops unrolled x4 (8 edges in flight/wave in
// agg1 - latency-exposure test), (b) nontemporal stores for offs/colb
// (streaming CSR data, skip L2 allocate).

#define FIN 128
#define C1 256   // H*D layer1
#define NH 8
#define HD 32
#define C2 64    // F_out
#define CH1 64

typedef float floatx2 __attribute__((ext_vector_type(2)));
typedef short bf16x8 __attribute__((ext_vector_type(8)));
typedef float f32x4 __attribute__((ext_vector_type(4)));

__device__ __forceinline__ float blo(unsigned u) { return __uint_as_float(u << 16); }
__device__ __forceinline__ float bhi(unsigned u) { return __uint_as_float(u & 0xffff0000u); }
__device__ __forceinline__ unsigned pkbf(float a, float b) {
    unsigned ua = __float_as_uint(a), ub = __float_as_uint(b);
    ua += 0x7fff + ((ua >> 16) & 1);
    ub += 0x7fff + ((ub >> 16) & 1);
    return (ua >> 16) | (ub & 0xffff0000u);
}

__global__ void zero_kernel(int* p, int n) {
    int i = blockIdx.x * 256 + threadIdx.x;
    if (i < n) p[i] = 0;
}

// 4 edges/thread: count in-degree AND record each edge's rank within its dst.
__global__ void hist_kernel(const int* __restrict__ ei, int E, int ETOT, int T,
                            int* cnt, int* __restrict__ offs) {
    int base = blockIdx.x * 256 + threadIdx.x;
    if (base >= T) return;
    int d[4], o[4];
    #pragma unroll
    for (int i = 0; i < 4; ++i) {
        int e = base + i * T;
        d[i] = (e < ETOT) ? ((e < E) ? ei[E + e] : (e - E)) : -1;
    }
    #pragma unroll
    for (int i = 0; i < 4; ++i)
        if (d[i] >= 0) o[i] = atomicAdd(&cnt[d[i]], 1);
    #pragma unroll
    for (int i = 0; i < 4; ++i)
        if (d[i] >= 0) __builtin_nontemporal_store(o[i], &offs[base + i * T]);
}

__global__ void scan1_kernel(const int* __restrict__ cnt, int n,
                             int* __restrict__ pref, int* __restrict__ bsum) {
    int tid = threadIdx.x, lane = tid & 63, w = tid >> 6;
    int i = blockIdx.x * 256 + tid;
    int v = (i < n) ? cnt[i] : 0;
    int sc = v;
    #pragma unroll
    for (int d = 1; d < 64; d <<= 1) {
        int t = __shfl_up(sc, d, 64);
        if (lane >= d) sc += t;
    }
    __shared__ int ws[4];
    if (lane == 63) ws[w] = sc;
    __syncthreads();
    int woff = 0;
    #pragma unroll
    for (int k = 0; k < 4; ++k) woff += (k < w) ? ws[k] : 0;
    if (i < n) pref[i] = woff + sc - v;
    if (tid == 255) bsum[blockIdx.x] = woff + sc;
}

__global__ void scan2_kernel(int* bsum, int nb) {
    int tid = threadIdx.x, lane = tid & 63, w = tid >> 6;
    int v = (tid < nb) ? bsum[tid] : 0;
    int sc = v;
    #pragma unroll
    for (int d = 1; d < 64; d <<= 1) {
        int t = __shfl_up(sc, d, 64);
        if (lane >= d) sc += t;
    }
    __shared__ int ws[4];
    if (lane == 63) ws[w] = sc;
    __syncthreads();
    int woff = 0;
    #pragma unroll
    for (int k = 0; k < 4; ++k) woff += (k < w) ? ws[k] : 0;
    __syncthreads();
    if (tid < nb) bsum[tid] = woff + sc - v;
}

__global__ void scan3_kernel(const int* __restrict__ pref, const int* __restrict__ bsum,
                             int n, int ETOT, int* __restrict__ rowptr) {
    int i = blockIdx.x * 256 + threadIdx.x;
    if (i < n) rowptr[i] = pref[i] + bsum[blockIdx.x];
    if (i == 0) rowptr[n] = ETOT;
}

__global__ void scatter_kernel(const int* __restrict__ ei, const int* __restrict__ rowptr,
                               const int* __restrict__ offs, int E, int ETOT, int T,
                               int* __restrict__ colb) {
    int base = blockIdx.x * 256 + threadIdx.x;
    if (base >= T) return;
    #pragma unroll
    for (int i = 0; i < 4; ++i) {
        int e = base + i * T;
        if (e >= ETOT) continue;
        int src, dst;
        if (e < E) { src = ei[e]; dst = ei[E + e]; }
        else       { src = e - E; dst = e - E; }
        __builtin_nontemporal_store(src, &colb[rowptr[dst] + offs[e]]);
    }
}

// ---- merged dtype prep ----
__global__ void prep_kernel(const float* __restrict__ x, const float* __restrict__ W1,
                            const float* __restrict__ W2, unsigned* __restrict__ xb,
                            unsigned short* __restrict__ w1t, unsigned short* __restrict__ w2t,
                            int total8) {
    int i = blockIdx.x * 256 + threadIdx.x;
    if (i < total8) {
        const float4* p = reinterpret_cast<const float4*>(x + (size_t)i * 8);
        float4 v0 = p[0], v1 = p[1];
        uint4 o;
        o.x = pkbf(v0.x, v0.y); o.y = pkbf(v0.z, v0.w);
        o.z = pkbf(v1.x, v1.y); o.w = pkbf(v1.z, v1.w);
        reinterpret_cast<uint4*>(xb)[i] = o;
        return;
    }
    int j1 = i - total8;
    if (j1 < C1 * FIN) {
        int j = j1 >> 7, k = j1 & 127;
        float v = W1[(size_t)k * C1 + j];
        w1t[j1] = (unsigned short)(pkbf(v, v) & 0xffffu);
        return;
    }
    int j2 = j1 - C1 * FIN;
    if (j2 < C2 * C1) {
        int j = j2 >> 8, k = j2 & 255;
        float v = W2[(size_t)k * C2 + j];
        w2t[j2] = (unsigned short)(pkbf(v, v) & 0xffffu);
    }
}

// ---- gemm1: h1[N,256] fp8 = xb[N,128] @ w1t^T + as1/ad1 epilogue ----
__global__ __launch_bounds__(256) void gemm1_mfma(
    const unsigned short* __restrict__ xb, const unsigned short* __restrict__ w1t,
    const float* __restrict__ att_s, const float* __restrict__ att_d,
    unsigned char* __restrict__ h1, float* __restrict__ as1, float* __restrict__ ad1, int Nn) {
    __shared__ __align__(16) unsigned char sA[64 * 256];
    int tid = threadIdx.x;
    int row0 = blockIdx.x * 64;
    #pragma unroll
    for (int rep = 0; rep < 4; ++rep) {
        int flat = rep * 256 + tid;
        int row = flat >> 4, c16 = flat & 15;
        uint4 v = make_uint4(0u, 0u, 0u, 0u);
        if (row0 + row < Nn)
            v = *reinterpret_cast<const uint4*>(
                reinterpret_cast<const unsigned char*>(xb) + (size_t)(row0 + row) * 256 + c16 * 16);
        *reinterpret_cast<uint4*>(sA + ((row * 256 + c16 * 16) ^ ((row & 7) << 4))) = v;
    }
    __syncthreads();
    int w = tid >> 6, l = tid & 63;
    int lr = l & 15, lq = l >> 4;
    int arow = w * 16 + lr;
    bf16x8 a[4];
    #pragma unroll
    for (int ks = 0; ks < 4; ++ks)
        a[ks] = *reinterpret_cast<const bf16x8*>(
            sA + ((arow * 256 + ks * 64 + lq * 16) ^ ((arow & 7) << 4)));
    const unsigned char* wb = reinterpret_cast<const unsigned char*>(w1t);
    float ps[4] = {0.f, 0.f, 0.f, 0.f}, pd[4] = {0.f, 0.f, 0.f, 0.f};
    #pragma unroll
    for (int nt = 0; nt < 16; ++nt) {
        f32x4 acc = {0.f, 0.f, 0.f, 0.f};
        #pragma unroll
        for (int ks = 0; ks < 4; ++ks) {
            bf16x8 b = *reinterpret_cast<const bf16x8*>(
                wb + (size_t)(nt * 16 + lr) * 256 + ks * 64 + lq * 16);
            acc = __builtin_amdgcn_mfma_f32_16x16x32_bf16(a[ks], b, acc, 0, 0, 0);
        }
        int col = nt * 16 + lr;
        float sa = att_s[col], da = att_d[col];
        #pragma unroll
        for (int reg = 0; reg < 4; ++reg) {
            int row = row0 + w * 16 + lq * 4 + reg;
            if (row < Nn) {
                unsigned pk = __builtin_amdgcn_cvt_pk_fp8_f32(acc[reg], acc[reg], 0, false);
                h1[(size_t)row * C1 + col] = (unsigned char)(pk & 0xffu);
            }
            ps[reg] = fmaf(acc[reg], sa, ps[reg]);
            pd[reg] = fmaf(acc[reg], da, pd[reg]);
        }
        if (nt & 1) {
            #pragma unroll
            for (int reg = 0; reg < 4; ++reg) {
                #pragma unroll
                for (int mk = 8; mk >= 1; mk >>= 1) {
                    ps[reg] += __shfl_xor(ps[reg], mk, 64);
                    pd[reg] += __shfl_xor(pd[reg], mk, 64);
                }
            }
            if (lr == 0) {
                int hh = nt >> 1;
                #pragma unroll
                for (int reg = 0; reg < 4; ++reg) {
                    int row = row0 + w * 16 + lq * 4 + reg;
                    if (row < Nn) {
                        as1[row * NH + hh] = ps[reg];
                        ad1[row * NH + hh] = pd[reg];
                    }
                }
            }
            #pragma unroll
            for (int reg = 0; reg < 4; ++reg) { ps[reg] = 0.f; pd[reg] = 0.f; }
        }
    }
}

// Layer-1 aggregation: 1 wave/node, 2 nodes/block; gather unroll x4.
__global__ __launch_bounds__(128) void agg1_kernel(
    const int* __restrict__ rowptr, const int* __restrict__ colb,
    const float* __restrict__ as1, const float* __restrict__ ad1,
    const unsigned char* __restrict__ h1, const float* __restrict__ b1,
    __hip_bfloat16* __restrict__ x1e, int N) {
    int wid = threadIdx.x >> 6, lane = threadIdx.x & 63;
    int n = blockIdx.x * 2 + wid;
    __shared__ float sp[2][CH1 * 9];
    __shared__ int soff[2][CH1];
    __shared__ float advs[2][NH];
    if (n >= N) return;
    int start = rowptr[n], end = rowptr[n + 1];
    int h = lane >> 3, sub = lane & 7;
    int half = lane >> 5, l5 = lane & 31;
    int hq = l5 >> 2;
    soff[wid][lane] = 0;
    if (lane < NH) advs[wid][lane] = ad1[n * NH + lane];
    float adr[NH];
    #pragma unroll
    for (int hh = 0; hh < NH; ++hh) adr[hh] = advs[wid][hh];

    float m = -INFINITY, denom = 0.f;
    floatx2 A01 = {0.f, 0.f}, A23 = {0.f, 0.f}, A45 = {0.f, 0.f}, A67 = {0.f, 0.f};
    for (int base = start; base < end; base += CH1) {
        int cn = min(CH1, end - base);
        if (lane < cn) {
            int s = colb[base + lane];
            soff[wid][lane] = s << 8;
            const float4* ap = reinterpret_cast<const float4*>(as1 + (size_t)s * NH);
            float4 q0 = ap[0], q1 = ap[1];
            float av[8] = {q0.x, q0.y, q0.z, q0.w, q1.x, q1.y, q1.z, q1.w};
            #pragma unroll
            for (int hh = 0; hh < NH; ++hh) {
                float e = av[hh] + adr[hh];
                e = e > 0.f ? e : 0.2f * e;
                sp[wid][lane * 9 + hh] = e;
            }
        }
        float cmax = -INFINITY;
        for (int e = sub; e < cn; e += 8) cmax = fmaxf(cmax, sp[wid][e * 9 + h]);
        #pragma unroll
        for (int mk = 4; mk >= 1; mk >>= 1) cmax = fmaxf(cmax, __shfl_xor(cmax, mk, 64));
        float newm = fmaxf(m, cmax);
        float scale = __expf(m - newm);
        float scale_g = __shfl(scale, hq << 3, 64);
        floatx2 s2 = {scale_g, scale_g};
        A01 *= s2; A23 *= s2; A45 *= s2; A67 *= s2;
        denom *= scale; m = newm;
        float psum = 0.f;
        for (int e = sub; e < cn; e += 8) {
            float p = __expf(sp[wid][e * 9 + h] - m);
            sp[wid][e * 9 + h] = p;
            psum += p;
        }
        #pragma unroll
        for (int mk = 4; mk >= 1; mk >>= 1) psum += __shfl_xor(psum, mk, 64);
        denom += psum;
        #pragma unroll 4
        for (int e2 = 0; e2 < cn; e2 += 2) {
            int e = e2 + half;
            bool ok = e < cn;
            int off = soff[wid][ok ? e : 0];
            float p = ok ? sp[wid][e * 9 + hq] : 0.f;
            floatx2 p2 = {p, p};
            uint2 u = *reinterpret_cast<const uint2*>(h1 + off + l5 * 8);
            floatx2 f01 = __builtin_amdgcn_cvt_pk_f32_fp8((int)u.x, false);
            floatx2 f23 = __builtin_amdgcn_cvt_pk_f32_fp8((int)u.x, true);
            floatx2 f45 = __builtin_amdgcn_cvt_pk_f32_fp8((int)u.y, false);
            floatx2 f67 = __builtin_amdgcn_cvt_pk_f32_fp8((int)u.y, true);
            A01 = __builtin_elementwise_fma(p2, f01, A01);
            A23 = __builtin_elementwise_fma(p2, f23, A23);
            A45 = __builtin_elementwise_fma(p2, f45, A45);
            A67 = __builtin_elementwise_fma(p2, f67, A67);
        }
    }
    float a0 = A01.x, a1 = A01.y, a2 = A23.x, a3 = A23.y;
    float a4 = A45.x, a5 = A45.y, a6 = A67.x, a7 = A67.y;
    a0 += __shfl_xor(a0, 32, 64); a1 += __shfl_xor(a1, 32, 64);
    a2 += __shfl_xor(a2, 32, 64); a3 += __shfl_xor(a3, 32, 64);
    a4 += __shfl_xor(a4, 32, 64); a5 += __shfl_xor(a5, 32, 64);
    a6 += __shfl_xor(a6, 32, 64); a7 += __shfl_xor(a7, 32, 64);
    float invd = 1.f / __shfl(denom, hq << 3, 64);
    if (half == 0) {
        const float4* bp = reinterpret_cast<const float4*>(b1 + l5 * 8);
        float4 bv0 = bp[0], bv1 = bp[1];
        float v0 = a0 * invd + bv0.x, v1 = a1 * invd + bv0.y;
        float v2 = a2 * invd + bv0.z, v3 = a3 * invd + bv0.w;
        float v4 = a4 * invd + bv1.x, v5 = a5 * invd + bv1.y;
        float v6 = a6 * invd + bv1.z, v7 = a7 * invd + bv1.w;
        v0 = v0 > 0.f ? v0 : __expf(v0) - 1.f;
        v1 = v1 > 0.f ? v1 : __expf(v1) - 1.f;
        v2 = v2 > 0.f ? v2 : __expf(v2) - 1.f;
        v3 = v3 > 0.f ? v3 : __expf(v3) - 1.f;
        v4 = v4 > 0.f ? v4 : __expf(v4) - 1.f;
        v5 = v5 > 0.f ? v5 : __expf(v5) - 1.f;
        v6 = v6 > 0.f ? v6 : __expf(v6) - 1.f;
        v7 = v7 > 0.f ? v7 : __expf(v7) - 1.f;
        uint4 w;
        w.x = pkbf(v0, v1); w.y = pkbf(v2, v3);
        w.z = pkbf(v4, v5); w.w = pkbf(v6, v7);
        *reinterpret_cast<uint4*>(x1e + (size_t)n * C1 + l5 * 8) = w;
    }
}

// ---- gemm2: h2[N,64] bf16 = x1e[N,256] @ w2t^T + as2/ad2 epilogue ----
__global__ __launch_bounds__(256) void gemm2_mfma(
    const unsigned short* __restrict__ x1e, const unsigned short* __restrict__ w2t,
    const float* __restrict__ att_s2, const float* __restrict__ att_d2,
    unsigned short* __restrict__ h2, float* __restrict__ as2, float* __restrict__ ad2, int Nn) {
    __shared__ __align__(16) unsigned char sA[64 * 512];
    int tid = threadIdx.x;
    int row0 = blockIdx.x * 64;
    #pragma unroll
    for (int rep = 0; rep < 8; ++rep) {
        int flat = rep * 256 + tid;
        int row = flat >> 5, c16 = flat & 31;
        uint4 v = make_uint4(0u, 0u, 0u, 0u);
        if (row0 + row < Nn)
            v = *reinterpret_cast<const uint4*>(
                reinterpret_cast<const unsigned char*>(x1e) + (size_t)(row0 + row) * 512 + c16 * 16);
        *reinterpret_cast<uint4*>(sA + ((row * 512 + c16 * 16) ^ ((row & 7) << 4))) = v;
    }
    __syncthreads();
    int w = tid >> 6, l = tid & 63;
    int lr = l & 15, lq = l >> 4;
    int arow = w * 16 + lr;
    bf16x8 a[8];
    #pragma unroll
    for (int ks = 0; ks < 8; ++ks)
        a[ks] = *reinterpret_cast<const bf16x8*>(
            sA + ((arow * 512 + ks * 64 + lq * 16) ^ ((arow & 7) << 4)));
    const unsigned char* wb = reinterpret_cast<const unsigned char*>(w2t);
    float ps[4] = {0.f, 0.f, 0.f, 0.f}, pd[4] = {0.f, 0.f, 0.f, 0.f};
    #pragma unroll
    for (int nt = 0; nt < 4; ++nt) {
        f32x4 acc = {0.f, 0.f, 0.f, 0.f};
        #pragma unroll
        for (int ks = 0; ks < 8; ++ks) {
            bf16x8 b = *reinterpret_cast<const bf16x8*>(
                wb + (size_t)(nt * 16 + lr) * 512 + ks * 64 + lq * 16);
            acc = __builtin_amdgcn_mfma_f32_16x16x32_bf16(a[ks], b, acc, 0, 0, 0);
        }
        int col = nt * 16 + lr;
        float sa = att_s2[col], da = att_d2[col];
        #pragma unroll
        for (int reg = 0; reg < 4; ++reg) {
            int row = row0 + w * 16 + lq * 4 + reg;
            if (row < Nn)
                h2[(size_t)row * C2 + col] = (unsigned short)(pkbf(acc[reg], acc[reg]) & 0xffffu);
            ps[reg] = fmaf(acc[reg], sa, ps[reg]);
            pd[reg] = fmaf(acc[reg], da, pd[reg]);
        }
    }
    #pragma unroll
    for (int reg = 0; reg < 4; ++reg) {
        #pragma unroll
        for (int mk = 8; mk >= 1; mk >>= 1) {
            ps[reg] += __shfl_xor(ps[reg], mk, 64);
            pd[reg] += __shfl_xor(pd[reg], mk, 64);
        }
    }
    if (lr == 0) {
        #pragma unroll
        for (int reg = 0; reg < 4; ++reg) {
            int row = row0 + w * 16 + lq * 4 + reg;
            if (row < Nn) { as2[row] = ps[reg]; ad2[row] = pd[reg]; }
        }
    }
}

// Layer-2 aggregation + bias + log_softmax. 1 wave/node, 2 nodes/block.
__global__ __launch_bounds__(128) void agg2_kernel(
    const int* __restrict__ rowptr, const int* __restrict__ colb,
    const float* __restrict__ as2, const float* __restrict__ ad2,
    const __hip_bfloat16* __restrict__ h2, const float* __restrict__ b2,
    float* __restrict__ out, int N) {
    int wid = threadIdx.x >> 6, lane = threadIdx.x & 63;
    int n = blockIdx.x * 2 + wid;
    __shared__ float sp2[2][64];
    __shared__ int soff2[2][64];
    if (n >= N) return;
    int start = rowptr[n], end = rowptr[n + 1];
    int q = lane >> 4, l4 = lane & 15;
    soff2[wid][lane] = 0;
    float adn = ad2[n];
    float m = -INFINITY, denom = 0.f;
    floatx2 A01 = {0.f, 0.f}, A23 = {0.f, 0.f};
    for (int base = start; base < end; base += 64) {
        int cn = min(64, end - base);
        float logit = -INFINITY;
        if (lane < cn) {
            int s = colb[base + lane];
            soff2[wid][lane] = s << 7;
            float e = as2[s] + adn;
            logit = e > 0.f ? e : 0.2f * e;
        }
        float cmax = logit;
        #pragma unroll
        for (int mk = 32; mk >= 1; mk >>= 1) cmax = fmaxf(cmax, __shfl_xor(cmax, mk, 64));
        float newm = fmaxf(m, cmax);
        float scale = __expf(m - newm);
        floatx2 s2 = {scale, scale};
        A01 *= s2; A23 *= s2;
        denom *= scale; m = newm;
        float p = (lane < cn) ? __expf(logit - m) : 0.f;
        sp2[wid][lane] = p;
        float psum = p;
        #pragma unroll
        for (int mk = 32; mk >= 1; mk >>= 1) psum += __shfl_xor(psum, mk, 64);
        denom += psum;
        #pragma unroll 4
        for (int e2 = 0; e2 < cn; e2 += 4) {
            int e = e2 + q;
            bool ok = e < cn;
            int off = soff2[wid][ok ? e : 0];
            float pe = ok ? sp2[wid][e] : 0.f;
            floatx2 p2 = {pe, pe};
            uint2 u = *reinterpret_cast<const uint2*>(
                reinterpret_cast<const unsigned char*>(h2) + off + l4 * 8);
            floatx2 f01 = {blo(u.x), bhi(u.x)};
            floatx2 f23 = {blo(u.y), bhi(u.y)};
            A01 = __builtin_elementwise_fma(p2, f01, A01);
            A23 = __builtin_elementwise_fma(p2, f23, A23);
        }
    }
    float a0 = A01.x, a1 = A01.y, a2 = A23.x, a3 = A23.y;
    a0 += __shfl_xor(a0, 16, 64); a1 += __shfl_xor(a1, 16, 64);
    a2 += __shfl_xor(a2, 16, 64); a3 += __shfl_xor(a3, 16, 64);
    a0 += __shfl_xor(a0, 32, 64); a1 += __shfl_xor(a1, 32, 64);
    a2 += __shfl_xor(a2, 32, 64); a3 += __shfl_xor(a3, 32, 64);
    float invd = 1.f / denom;
    const float4* bp = reinterpret_cast<const float4*>(b2 + l4 * 4);
    float4 bv = bp[0];
    float v0 = a0 * invd + bv.x, v1 = a1 * invd + bv.y;
    float v2 = a2 * invd + bv.z, v3 = a3 * invd + bv.w;
    float mx = fmaxf(fmaxf(v0, v1), fmaxf(v2, v3));
    #pragma unroll
    for (int mk = 8; mk >= 1; mk >>= 1) mx = fmaxf(mx, __shfl_xor(mx, mk, 64));
    float sum = __expf(v0 - mx) + __expf(v1 - mx) + __expf(v2 - mx) + __expf(v3 - mx);
    #pragma unroll
    for (int mk = 8; mk >= 1; mk >>= 1) sum += __shfl_xor(sum, mk, 64);
    float ls = logf(sum);
    if (q == 0) {
        float4 o = make_float4(v0 - mx - ls, v1 - mx - ls, v2 - mx - ls, v3 - mx - ls);
        *reinterpret_cast<float4*>(out + (size_t)n * C2 + l4 * 4) = o;
    }
}

extern "C" void kernel_launch(void* const* d_in, const int* in_sizes, int n_in,
                              void* d_out, int out_size, void* d_ws, size_t ws_size,
                              hipStream_t stream) {
    const float* x      = (const float*)d_in[0];
    const int*   ei     = (const int*)d_in[1];
    const float* W1     = (const float*)d_in[2];
    const float* att_s1 = (const float*)d_in[3];
    const float* att_d1 = (const float*)d_in[4];
    const float* b1     = (const float*)d_in[5];
    const float* W2     = (const float*)d_in[6];
    const float* att_s2 = (const float*)d_in[7];
    const float* att_d2 = (const float*)d_in[8];
    const float* b2     = (const float*)d_in[9];
    float* out = (float*)d_out;

    const int N = out_size / C2;          // 50000
    const int E = in_sizes[1] / 2;        // 1.6M
    const int ETOT = E + N;
    const int NB = (N + 255) / 256;

    char* ws = (char*)d_ws;
    size_t off = 0;
    auto alloc = [&](size_t bytes) -> void* {
        void* p = ws + off;
        off += (bytes + 255) & ~(size_t)255;
        return p;
    };
    unsigned char* h1 = (unsigned char*)alloc((size_t)N * C1);           // 12.8 MB fp8
    __hip_bfloat16* x1e = (__hip_bfloat16*)alloc((size_t)N * C1 * 2);    // 25.6 MB bf16
    unsigned* xb = (unsigned*)alloc((size_t)N * FIN * 2);                // 12.8 MB bf16
    unsigned short* w1t = (unsigned short*)alloc((size_t)C1 * FIN * 2);
    unsigned short* w2t = (unsigned short*)alloc((size_t)C2 * C1 * 2);
    float* as1  = (float*)alloc((size_t)N * NH * 4);
    float* ad1  = (float*)alloc((size_t)N * NH * 4);
    float* as2  = (float*)alloc((size_t)N * 4);
    float* ad2  = (float*)alloc((size_t)N * 4);
    int*   cnt    = (int*)alloc((size_t)N * 4);
    int*   rowptr = (int*)alloc((size_t)(N + 1) * 4);
    int*   pref   = (int*)alloc((size_t)N * 4);
    int*   bsum   = (int*)alloc((size_t)NB * 4);
    int*   offs   = (int*)alloc((size_t)ETOT * 4);
    int*   colb   = (int*)alloc((size_t)ETOT * 4);
    unsigned short* h2 = (unsigned short*)h1;   // reuse after agg1

    // --- CSR build ---
    const int T = (ETOT + 3) / 4;
    zero_kernel<<<(N + 255) / 256, 256, 0, stream>>>(cnt, N);
    hist_kernel<<<(T + 255) / 256, 256, 0, stream>>>(ei, E, ETOT, T, cnt, offs);
    scan1_kernel<<<NB, 256, 0, stream>>>(cnt, N, pref, bsum);
    scan2_kernel<<<1, 256, 0, stream>>>(bsum, NB);
    scan3_kernel<<<NB, 256, 0, stream>>>(pref, bsum, N, ETOT, rowptr);
    scatter_kernel<<<(T + 255) / 256, 256, 0, stream>>>(ei, rowptr, offs, E, ETOT, T, colb);

    // --- dtype prep (merged) ---
    int total8 = N * FIN / 8;
    int prep_total = total8 + C1 * FIN + C2 * C1;
    prep_kernel<<<(prep_total + 255) / 256, 256, 0, stream>>>(x, W1, W2, xb, w1t, w2t, total8);

    // --- Layer 1 ---
    gemm1_mfma<<<(N + 63) / 64, 256, 0, stream>>>((const unsigned short*)xb, w1t,
                                                  att_s1, att_d1, h1, as1, ad1, N);
    agg1_kernel<<<(N + 1) / 2, 128, 0, stream>>>(rowptr, colb, as1, ad1, h1, b1, x1e, N);

    // --- Layer 2 ---
    gemm2_mfma<<<(N + 63) / 64, 256, 0, stream>>>((const unsigned short*)x1e, w2t,
                                                  att_s2, att_d2, h2, as2, ad2, N);
    agg2_kernel<<<(N + 1) / 2, 128, 0, stream>>>(rowptr, colb, as2, ad2,
                                                 (const __hip_bfloat16*)h2, b2, out, N);
}

// Round 13
// 282.023 us; speedup vs baseline: 1.1295x; 1.1295x over previous
//
#include <hip/hip_runtime.h>
#include <hip/hip_bf16.h>
#include <math.h>

// GAT 2-layer forward for MI355X.
// R13 = R11 (best: 286us) + (a) gemm1 stages x directly from f32 (drops
// prep x-pass + xb buffer), (b) self-loop prefill in scan3 (cnt init 1,
// colb[rowptr[n]]=n; hist/scatter do only real edges), (c) no nontemporal.

#define FIN 128
#define C1 256   // H*D layer1
#define NH 8
#define HD 32
#define C2 64    // F_out
#define CH1 64

typedef float floatx2 __attribute__((ext_vector_type(2)));
typedef short bf16x8 __attribute__((ext_vector_type(8)));
typedef float f32x4 __attribute__((ext_vector_type(4)));

__device__ __forceinline__ float blo(unsigned u) { return __uint_as_float(u << 16); }
__device__ __forceinline__ float bhi(unsigned u) { return __uint_as_float(u & 0xffff0000u); }
__device__ __forceinline__ unsigned pkbf(float a, float b) {
    unsigned ua = __float_as_uint(a), ub = __float_as_uint(b);
    ua += 0x7fff + ((ua >> 16) & 1);
    ub += 0x7fff + ((ub >> 16) & 1);
    return (ua >> 16) | (ub & 0xffff0000u);
}

__global__ void one_kernel(int* p, int n) {
    int i = blockIdx.x * 256 + threadIdx.x;
    if (i < n) p[i] = 1;               // rank 0 reserved for the self-loop
}

// 4 real edges/thread: count in-degree AND record each edge's rank (>=1).
__global__ void hist_kernel(const int* __restrict__ ei, int E, int T,
                            int* cnt, int* __restrict__ offs) {
    int base = blockIdx.x * 256 + threadIdx.x;
    if (base >= T) return;
    int d[4], o[4];
    #pragma unroll
    for (int i = 0; i < 4; ++i) {
        int e = base + i * T;
        d[i] = (e < E) ? ei[E + e] : -1;
    }
    #pragma unroll
    for (int i = 0; i < 4; ++i)
        if (d[i] >= 0) o[i] = atomicAdd(&cnt[d[i]], 1);
    #pragma unroll
    for (int i = 0; i < 4; ++i)
        if (d[i] >= 0) offs[base + i * T] = o[i];
}

__global__ void scan1_kernel(const int* __restrict__ cnt, int n,
                             int* __restrict__ pref, int* __restrict__ bsum) {
    int tid = threadIdx.x, lane = tid & 63, w = tid >> 6;
    int i = blockIdx.x * 256 + tid;
    int v = (i < n) ? cnt[i] : 0;
    int sc = v;
    #pragma unroll
    for (int d = 1; d < 64; d <<= 1) {
        int t = __shfl_up(sc, d, 64);
        if (lane >= d) sc += t;
    }
    __shared__ int ws[4];
    if (lane == 63) ws[w] = sc;
    __syncthreads();
    int woff = 0;
    #pragma unroll
    for (int k = 0; k < 4; ++k) woff += (k < w) ? ws[k] : 0;
    if (i < n) pref[i] = woff + sc - v;
    if (tid == 255) bsum[blockIdx.x] = woff + sc;
}

__global__ void scan2_kernel(int* bsum, int nb) {
    int tid = threadIdx.x, lane = tid & 63, w = tid >> 6;
    int v = (tid < nb) ? bsum[tid] : 0;
    int sc = v;
    #pragma unroll
    for (int d = 1; d < 64; d <<= 1) {
        int t = __shfl_up(sc, d, 64);
        if (lane >= d) sc += t;
    }
    __shared__ int ws[4];
    if (lane == 63) ws[w] = sc;
    __syncthreads();
    int woff = 0;
    #pragma unroll
    for (int k = 0; k < 4; ++k) woff += (k < w) ? ws[k] : 0;
    __syncthreads();
    if (tid < nb) bsum[tid] = woff + sc - v;
}

// writes rowptr AND places the self-loop at rank 0 of each segment.
__global__ void scan3_kernel(const int* __restrict__ pref, const int* __restrict__ bsum,
                             int n, int ETOT, int* __restrict__ rowptr,
                             int* __restrict__ colb) {
    int i = blockIdx.x * 256 + threadIdx.x;
    if (i < n) {
        int rp = pref[i] + bsum[blockIdx.x];
        rowptr[i] = rp;
        colb[rp] = i;                  // self loop, rank 0
    }
    if (i == 0) rowptr[n] = ETOT;
}

__global__ void scatter_kernel(const int* __restrict__ ei, const int* __restrict__ rowptr,
                               const int* __restrict__ offs, int E, int T,
                               int* __restrict__ colb) {
    int base = blockIdx.x * 256 + threadIdx.x;
    if (base >= T) return;
    #pragma unroll
    for (int i = 0; i < 4; ++i) {
        int e = base + i * T;
        if (e >= E) continue;
        int src = ei[e], dst = ei[E + e];
        colb[rowptr[dst] + offs[e]] = src;
    }
}

// ---- weight prep: W1 -> w1t [256][128] bf16, W2 -> w2t [64][256] bf16 ----
__global__ void prepw_kernel(const float* __restrict__ W1, const float* __restrict__ W2,
                             unsigned short* __restrict__ w1t, unsigned short* __restrict__ w2t) {
    int i = blockIdx.x * 256 + threadIdx.x;
    if (i < C1 * FIN) {
        int j = i >> 7, k = i & 127;
        float v = W1[(size_t)k * C1 + j];
        w1t[i] = (unsigned short)(pkbf(v, v) & 0xffffu);
        return;
    }
    int j2 = i - C1 * FIN;
    if (j2 < C2 * C1) {
        int j = j2 >> 8, k = j2 & 255;
        float v = W2[(size_t)k * C2 + j];
        w2t[j2] = (unsigned short)(pkbf(v, v) & 0xffffu);
    }
}

// ---- gemm1: h1[N,256] fp8 = x[N,128](f32, converted in staging) @ w1t^T ----
__global__ __launch_bounds__(256) void gemm1_mfma(
    const float* __restrict__ x, const unsigned short* __restrict__ w1t,
    const float* __restrict__ att_s, const float* __restrict__ att_d,
    unsigned char* __restrict__ h1, float* __restrict__ as1, float* __restrict__ ad1, int Nn) {
    __shared__ __align__(16) unsigned char sA[64 * 256];
    int tid = threadIdx.x;
    int row0 = blockIdx.x * 64;
    #pragma unroll
    for (int rep = 0; rep < 4; ++rep) {
        int flat = rep * 256 + tid;
        int row = flat >> 4, c16 = flat & 15;    // 16B bf16 chunk = 8 elems
        uint4 v = make_uint4(0u, 0u, 0u, 0u);
        if (row0 + row < Nn) {
            const float4* p = reinterpret_cast<const float4*>(
                x + (size_t)(row0 + row) * FIN + c16 * 8);
            float4 f0 = p[0], f1 = p[1];
            v.x = pkbf(f0.x, f0.y); v.y = pkbf(f0.z, f0.w);
            v.z = pkbf(f1.x, f1.y); v.w = pkbf(f1.z, f1.w);
        }
        *reinterpret_cast<uint4*>(sA + ((row * 256 + c16 * 16) ^ ((row & 7) << 4))) = v;
    }
    __syncthreads();
    int w = tid >> 6, l = tid & 63;
    int lr = l & 15, lq = l >> 4;
    int arow = w * 16 + lr;
    bf16x8 a[4];
    #pragma unroll
    for (int ks = 0; ks < 4; ++ks)
        a[ks] = *reinterpret_cast<const bf16x8*>(
            sA + ((arow * 256 + ks * 64 + lq * 16) ^ ((arow & 7) << 4)));
    const unsigned char* wb = reinterpret_cast<const unsigned char*>(w1t);
    float ps[4] = {0.f, 0.f, 0.f, 0.f}, pd[4] = {0.f, 0.f, 0.f, 0.f};
    #pragma unroll
    for (int nt = 0; nt < 16; ++nt) {
        f32x4 acc = {0.f, 0.f, 0.f, 0.f};
        #pragma unroll
        for (int ks = 0; ks < 4; ++ks) {
            bf16x8 b = *reinterpret_cast<const bf16x8*>(
                wb + (size_t)(nt * 16 + lr) * 256 + ks * 64 + lq * 16);
            acc = __builtin_amdgcn_mfma_f32_16x16x32_bf16(a[ks], b, acc, 0, 0, 0);
        }
        int col = nt * 16 + lr;
        float sa = att_s[col], da = att_d[col];
        #pragma unroll
        for (int reg = 0; reg < 4; ++reg) {
            int row = row0 + w * 16 + lq * 4 + reg;
            if (row < Nn) {
                unsigned pk = __builtin_amdgcn_cvt_pk_fp8_f32(acc[reg], acc[reg], 0, false);
                h1[(size_t)row * C1 + col] = (unsigned char)(pk & 0xffu);
            }
            ps[reg] = fmaf(acc[reg], sa, ps[reg]);
            pd[reg] = fmaf(acc[reg], da, pd[reg]);
        }
        if (nt & 1) {
            #pragma unroll
            for (int reg = 0; reg < 4; ++reg) {
                #pragma unroll
                for (int mk = 8; mk >= 1; mk >>= 1) {
                    ps[reg] += __shfl_xor(ps[reg], mk, 64);
                    pd[reg] += __shfl_xor(pd[reg], mk, 64);
                }
            }
            if (lr == 0) {
                int hh = nt >> 1;
                #pragma unroll
                for (int reg = 0; reg < 4; ++reg) {
                    int row = row0 + w * 16 + lq * 4 + reg;
                    if (row < Nn) {
                        as1[row * NH + hh] = ps[reg];
                        ad1[row * NH + hh] = pd[reg];
                    }
                }
            }
            #pragma unroll
            for (int reg = 0; reg < 4; ++reg) { ps[reg] = 0.f; pd[reg] = 0.f; }
        }
    }
}

// Layer-1 aggregation: 1 wave/node, 2 nodes/block, 2 edges/iter (R11 form).
__global__ __launch_bounds__(128) void agg1_kernel(
    const int* __restrict__ rowptr, const int* __restrict__ colb,
    const float* __restrict__ as1, const float* __restrict__ ad1,
    const unsigned char* __restrict__ h1, const float* __restrict__ b1,
    __hip_bfloat16* __restrict__ x1e, int N) {
    int wid = threadIdx.x >> 6, lane = threadIdx.x & 63;
    int n = blockIdx.x * 2 + wid;
    __shared__ float sp[2][CH1 * 9];
    __shared__ int soff[2][CH1];
    __shared__ float advs[2][NH];
    if (n >= N) return;
    int start = rowptr[n], end = rowptr[n + 1];
    int h = lane >> 3, sub = lane & 7;
    int half = lane >> 5, l5 = lane & 31;
    int hq = l5 >> 2;
    soff[wid][lane] = 0;
    if (lane < NH) advs[wid][lane] = ad1[n * NH + lane];
    float adr[NH];
    #pragma unroll
    for (int hh = 0; hh < NH; ++hh) adr[hh] = advs[wid][hh];

    float m = -INFINITY, denom = 0.f;
    floatx2 A01 = {0.f, 0.f}, A23 = {0.f, 0.f}, A45 = {0.f, 0.f}, A67 = {0.f, 0.f};
    for (int base = start; base < end; base += CH1) {
        int cn = min(CH1, end - base);
        if (lane < cn) {
            int s = colb[base + lane];
            soff[wid][lane] = s << 8;
            const float4* ap = reinterpret_cast<const float4*>(as1 + (size_t)s * NH);
            float4 q0 = ap[0], q1 = ap[1];
            float av[8] = {q0.x, q0.y, q0.z, q0.w, q1.x, q1.y, q1.z, q1.w};
            #pragma unroll
            for (int hh = 0; hh < NH; ++hh) {
                float e = av[hh] + adr[hh];
                e = e > 0.f ? e : 0.2f * e;
                sp[wid][lane * 9 + hh] = e;
            }
        }
        float cmax = -INFINITY;
        for (int e = sub; e < cn; e += 8) cmax = fmaxf(cmax, sp[wid][e * 9 + h]);
        #pragma unroll
        for (int mk = 4; mk >= 1; mk >>= 1) cmax = fmaxf(cmax, __shfl_xor(cmax, mk, 64));
        float newm = fmaxf(m, cmax);
        float scale = __expf(m - newm);
        float scale_g = __shfl(scale, hq << 3, 64);
        floatx2 s2 = {scale_g, scale_g};
        A01 *= s2; A23 *= s2; A45 *= s2; A67 *= s2;
        denom *= scale; m = newm;
        float psum = 0.f;
        for (int e = sub; e < cn; e += 8) {
            float p = __expf(sp[wid][e * 9 + h] - m);
            sp[wid][e * 9 + h] = p;
            psum += p;
        }
        #pragma unroll
        for (int mk = 4; mk >= 1; mk >>= 1) psum += __shfl_xor(psum, mk, 64);
        denom += psum;
        #pragma unroll 2
        for (int e2 = 0; e2 < cn; e2 += 2) {
            int e = e2 + half;
            bool ok = e < cn;
            int off = soff[wid][ok ? e : 0];
            float p = ok ? sp[wid][e * 9 + hq] : 0.f;
            floatx2 p2 = {p, p};
            uint2 u = *reinterpret_cast<const uint2*>(h1 + off + l5 * 8);
            floatx2 f01 = __builtin_amdgcn_cvt_pk_f32_fp8((int)u.x, false);
            floatx2 f23 = __builtin_amdgcn_cvt_pk_f32_fp8((int)u.x, true);
            floatx2 f45 = __builtin_amdgcn_cvt_pk_f32_fp8((int)u.y, false);
            floatx2 f67 = __builtin_amdgcn_cvt_pk_f32_fp8((int)u.y, true);
            A01 = __builtin_elementwise_fma(p2, f01, A01);
            A23 = __builtin_elementwise_fma(p2, f23, A23);
            A45 = __builtin_elementwise_fma(p2, f45, A45);
            A67 = __builtin_elementwise_fma(p2, f67, A67);
        }
    }
    float a0 = A01.x, a1 = A01.y, a2 = A23.x, a3 = A23.y;
    float a4 = A45.x, a5 = A45.y, a6 = A67.x, a7 = A67.y;
    a0 += __shfl_xor(a0, 32, 64); a1 += __shfl_xor(a1, 32, 64);
    a2 += __shfl_xor(a2, 32, 64); a3 += __shfl_xor(a3, 32, 64);
    a4 += __shfl_xor(a4, 32, 64); a5 += __shfl_xor(a5, 32, 64);
    a6 += __shfl_xor(a6, 32, 64); a7 += __shfl_xor(a7, 32, 64);
    float invd = 1.f / __shfl(denom, hq << 3, 64);
    if (half == 0) {
        const float4* bp = reinterpret_cast<const float4*>(b1 + l5 * 8);
        float4 bv0 = bp[0], bv1 = bp[1];
        float v0 = a0 * invd + bv0.x, v1 = a1 * invd + bv0.y;
        float v2 = a2 * invd + bv0.z, v3 = a3 * invd + bv0.w;
        float v4 = a4 * invd + bv1.x, v5 = a5 * invd + bv1.y;
        float v6 = a6 * invd + bv1.z, v7 = a7 * invd + bv1.w;
        v0 = v0 > 0.f ? v0 : __expf(v0) - 1.f;
        v1 = v1 > 0.f ? v1 : __expf(v1) - 1.f;
        v2 = v2 > 0.f ? v2 : __expf(v2) - 1.f;
        v3 = v3 > 0.f ? v3 : __expf(v3) - 1.f;
        v4 = v4 > 0.f ? v4 : __expf(v4) - 1.f;
        v5 = v5 > 0.f ? v5 : __expf(v5) - 1.f;
        v6 = v6 > 0.f ? v6 : __expf(v6) - 1.f;
        v7 = v7 > 0.f ? v7 : __expf(v7) - 1.f;
        uint4 w;
        w.x = pkbf(v0, v1); w.y = pkbf(v2, v3);
        w.z = pkbf(v4, v5); w.w = pkbf(v6, v7);
        *reinterpret_cast<uint4*>(x1e + (size_t)n * C1 + l5 * 8) = w;
    }
}

// ---- gemm2: h2[N,64] bf16 = x1e[N,256] @ w2t^T + as2/ad2 epilogue ----
__global__ __launch_bounds__(256) void gemm2_mfma(
    const unsigned short* __restrict__ x1e, const unsigned short* __restrict__ w2t,
    const float* __restrict__ att_s2, const float* __restrict__ att_d2,
    unsigned short* __restrict__ h2, float* __restrict__ as2, float* __restrict__ ad2, int Nn) {
    __shared__ __align__(16) unsigned char sA[64 * 512];
    int tid = threadIdx.x;
    int row0 = blockIdx.x * 64;
    #pragma unroll
    for (int rep = 0; rep < 8; ++rep) {
        int flat = rep * 256 + tid;
        int row = flat >> 5, c16 = flat & 31;
        uint4 v = make_uint4(0u, 0u, 0u, 0u);
        if (row0 + row < Nn)
            v = *reinterpret_cast<const uint4*>(
                reinterpret_cast<const unsigned char*>(x1e) + (size_t)(row0 + row) * 512 + c16 * 16);
        *reinterpret_cast<uint4*>(sA + ((row * 512 + c16 * 16) ^ ((row & 7) << 4))) = v;
    }
    __syncthreads();
    int w = tid >> 6, l = tid & 63;
    int lr = l & 15, lq = l >> 4;
    int arow = w * 16 + lr;
    bf16x8 a[8];
    #pragma unroll
    for (int ks = 0; ks < 8; ++ks)
        a[ks] = *reinterpret_cast<const bf16x8*>(
            sA + ((arow * 512 + ks * 64 + lq * 16) ^ ((arow & 7) << 4)));
    const unsigned char* wb = reinterpret_cast<const unsigned char*>(w2t);
    float ps[4] = {0.f, 0.f, 0.f, 0.f}, pd[4] = {0.f, 0.f, 0.f, 0.f};
    #pragma unroll
    for (int nt = 0; nt < 4; ++nt) {
        f32x4 acc = {0.f, 0.f, 0.f, 0.f};
        #pragma unroll
        for (int ks = 0; ks < 8; ++ks) {
            bf16x8 b = *reinterpret_cast<const bf16x8*>(
                wb + (size_t)(nt * 16 + lr) * 512 + ks * 64 + lq * 16);
            acc = __builtin_amdgcn_mfma_f32_16x16x32_bf16(a[ks], b, acc, 0, 0, 0);
        }
        int col = nt * 16 + lr;
        float sa = att_s2[col], da = att_d2[col];
        #pragma unroll
        for (int reg = 0; reg < 4; ++reg) {
            int row = row0 + w * 16 + lq * 4 + reg;
            if (row < Nn)
                h2[(size_t)row * C2 + col] = (unsigned short)(pkbf(acc[reg], acc[reg]) & 0xffffu);
            ps[reg] = fmaf(acc[reg], sa, ps[reg]);
            pd[reg] = fmaf(acc[reg], da, pd[reg]);
        }
    }
    #pragma unroll
    for (int reg = 0; reg < 4; ++reg) {
        #pragma unroll
        for (int mk = 8; mk >= 1; mk >>= 1) {
            ps[reg] += __shfl_xor(ps[reg], mk, 64);
            pd[reg] += __shfl_xor(pd[reg], mk, 64);
        }
    }
    if (lr == 0) {
        #pragma unroll
        for (int reg = 0; reg < 4; ++reg) {
            int row = row0 + w * 16 + lq * 4 + reg;
            if (row < Nn) { as2[row] = ps[reg]; ad2[row] = pd[reg]; }
        }
    }
}

// Layer-2 aggregation + bias + log_softmax. 1 wave/node, 2 nodes/block.
__global__ __launch_bounds__(128) void agg2_kernel(
    const int* __restrict__ rowptr, const int* __restrict__ colb,
    const float* __restrict__ as2, const float* __restrict__ ad2,
    const __hip_bfloat16* __restrict__ h2, const float* __restrict__ b2,
    float* __restrict__ out, int N) {
    int wid = threadIdx.x >> 6, lane = threadIdx.x & 63;
    int n = blockIdx.x * 2 + wid;
    __shared__ float sp2[2][64];
    __shared__ int soff2[2][64];
    if (n >= N) return;
    int start = rowptr[n], end = rowptr[n + 1];
    int q = lane >> 4, l4 = lane & 15;
    soff2[wid][lane] = 0;
    float adn = ad2[n];
    float m = -INFINITY, denom = 0.f;
    floatx2 A01 = {0.f, 0.f}, A23 = {0.f, 0.f};
    for (int base = start; base < end; base += 64) {
        int cn = min(64, end - base);
        float logit = -INFINITY;
        if (lane < cn) {
            int s = colb[base + lane];
            soff2[wid][lane] = s << 7;
            float e = as2[s] + adn;
            logit = e > 0.f ? e : 0.2f * e;
        }
        float cmax = logit;
        #pragma unroll
        for (int mk = 32; mk >= 1; mk >>= 1) cmax = fmaxf(cmax, __shfl_xor(cmax, mk, 64));
        float newm = fmaxf(m, cmax);
        float scale = __expf(m - newm);
        floatx2 s2 = {scale, scale};
        A01 *= s2; A23 *= s2;
        denom *= scale; m = newm;
        float p = (lane < cn) ? __expf(logit - m) : 0.f;
        sp2[wid][lane] = p;
        float psum = p;
        #pragma unroll
        for (int mk = 32; mk >= 1; mk >>= 1) psum += __shfl_xor(psum, mk, 64);
        denom += psum;
        #pragma unroll 2
        for (int e2 = 0; e2 < cn; e2 += 4) {
            int e = e2 + q;
            bool ok = e < cn;
            int off = soff2[wid][ok ? e : 0];
            float pe = ok ? sp2[wid][e] : 0.f;
            floatx2 p2 = {pe, pe};
            uint2 u = *reinterpret_cast<const uint2*>(
                reinterpret_cast<const unsigned char*>(h2) + off + l4 * 8);
            floatx2 f01 = {blo(u.x), bhi(u.x)};
            floatx2 f23 = {blo(u.y), bhi(u.y)};
            A01 = __builtin_elementwise_fma(p2, f01, A01);
            A23 = __builtin_elementwise_fma(p2, f23, A23);
        }
    }
    float a0 = A01.x, a1 = A01.y, a2 = A23.x, a3 = A23.y;
    a0 += __shfl_xor(a0, 16, 64); a1 += __shfl_xor(a1, 16, 64);
    a2 += __shfl_xor(a2, 16, 64); a3 += __shfl_xor(a3, 16, 64);
    a0 += __shfl_xor(a0, 32, 64); a1 += __shfl_xor(a1, 32, 64);
    a2 += __shfl_xor(a2, 32, 64); a3 += __shfl_xor(a3, 32, 64);
    float invd = 1.f / denom;
    const float4* bp = reinterpret_cast<const float4*>(b2 + l4 * 4);
    float4 bv = bp[0];
    float v0 = a0 * invd + bv.x, v1 = a1 * invd + bv.y;
    float v2 = a2 * invd + bv.z, v3 = a3 * invd + bv.w;
    float mx = fmaxf(fmaxf(v0, v1), fmaxf(v2, v3));
    #pragma unroll
    for (int mk = 8; mk >= 1; mk >>= 1) mx = fmaxf(mx, __shfl_xor(mx, mk, 64));
    float sum = __expf(v0 - mx) + __expf(v1 - mx) + __expf(v2 - mx) + __expf(v3 - mx);
    #pragma unroll
    for (int mk = 8; mk >= 1; mk >>= 1) sum += __shfl_xor(sum, mk, 64);
    float ls = logf(sum);
    if (q == 0) {
        float4 o = make_float4(v0 - mx - ls, v1 - mx - ls, v2 - mx - ls, v3 - mx - ls);
        *reinterpret_cast<float4*>(out + (size_t)n * C2 + l4 * 4) = o;
    }
}

extern "C" void kernel_launch(void* const* d_in, const int* in_sizes, int n_in,
                              void* d_out, int out_size, void* d_ws, size_t ws_size,
                              hipStream_t stream) {
    const float* x      = (const float*)d_in[0];
    const int*   ei     = (const int*)d_in[1];
    const float* W1     = (const float*)d_in[2];
    const float* att_s1 = (const float*)d_in[3];
    const float* att_d1 = (const float*)d_in[4];
    const float* b1     = (const float*)d_in[5];
    const float* W2     = (const float*)d_in[6];
    const float* att_s2 = (const float*)d_in[7];
    const float* att_d2 = (const float*)d_in[8];
    const float* b2     = (const float*)d_in[9];
    float* out = (float*)d_out;

    const int N = out_size / C2;          // 50000
    const int E = in_sizes[1] / 2;        // 1.6M
    const int ETOT = E + N;
    const int NB = (N + 255) / 256;

    char* ws = (char*)d_ws;
    size_t off = 0;
    auto alloc = [&](size_t bytes) -> void* {
        void* p = ws + off;
        off += (bytes + 255) & ~(size_t)255;
        return p;
    };
    unsigned char* h1 = (unsigned char*)alloc((size_t)N * C1);           // 12.8 MB fp8
    __hip_bfloat16* x1e = (__hip_bfloat16*)alloc((size_t)N * C1 * 2);    // 25.6 MB bf16
    unsigned short* w1t = (unsigned short*)alloc((size_t)C1 * FIN * 2);
    unsigned short* w2t = (unsigned short*)alloc((size_t)C2 * C1 * 2);
    float* as1  = (float*)alloc((size_t)N * NH * 4);
    float* ad1  = (float*)alloc((size_t)N * NH * 4);
    float* as2  = (float*)alloc((size_t)N * 4);
    float* ad2  = (float*)alloc((size_t)N * 4);
    int*   cnt    = (int*)alloc((size_t)N * 4);
    int*   rowptr = (int*)alloc((size_t)(N + 1) * 4);
    int*   pref   = (int*)alloc((size_t)N * 4);
    int*   bsum   = (int*)alloc((size_t)NB * 4);
    int*   offs   = (int*)alloc((size_t)E * 4);
    int*   colb   = (int*)alloc((size_t)ETOT * 4);
    unsigned short* h2 = (unsigned short*)h1;   // reuse after agg1

    // --- CSR build (self-loops prefilled at rank 0 via scan3) ---
    const int T = (E + 3) / 4;
    one_kernel<<<(N + 255) / 256, 256, 0, stream>>>(cnt, N);
    hist_kernel<<<(T + 255) / 256, 256, 0, stream>>>(ei, E, T, cnt, offs);
    scan1_kernel<<<NB, 256, 0, stream>>>(cnt, N, pref, bsum);
    scan2_kernel<<<1, 256, 0, stream>>>(bsum, NB);
    scan3_kernel<<<NB, 256, 0, stream>>>(pref, bsum, N, ETOT, rowptr, colb);
    scatter_kernel<<<(T + 255) / 256, 256, 0, stream>>>(ei, rowptr, offs, E, T, colb);

    // --- weight prep ---
    int prep_total = C1 * FIN + C2 * C1;
    prepw_kernel<<<(prep_total + 255) / 256, 256, 0, stream>>>(W1, W2, w1t, w2t);

    // --- Layer 1 ---
    gemm1_mfma<<<(N + 63) / 64, 256, 0, stream>>>(x, w1t, att_s1, att_d1, h1, as1, ad1, N);
    agg1_kernel<<<(N + 1) / 2, 128, 0, stream>>>(rowptr, colb, as1, ad1, h1, b1, x1e, N);

    // --- Layer 2 ---
    gemm2_mfma<<<(N + 63) / 64, 256, 0, stream>>>((const unsigned short*)x1e, w2t,
                                                  att_s2, att_d2, h2, as2, ad2, N);
    agg2_kernel<<<(N + 1) / 2, 128, 0, stream>>>(rowptr, colb, as2, ad2,
                                                 (const __hip_bfloat16*)h2, b2, out, N);
}

// Round 14
// 275.746 us; speedup vs baseline: 1.1552x; 1.0228x over previous
//
#include <hip/hip_runtime.h>
#include <hip/hip_bf16.h>
#include <math.h>

// GAT 2-layer forward for MI355X.
// R14 = R13 + h2 stored fp8 (3.2MB -> ~fits per-XCD L2; halves agg2 gather
// bytes; gemm2 converts from f32 acc directly) + one/prepw merged.

#define FIN 128
#define C1 256   // H*D layer1
#define NH 8
#define HD 32
#define C2 64    // F_out
#define CH1 64

typedef float floatx2 __attribute__((ext_vector_type(2)));
typedef short bf16x8 __attribute__((ext_vector_type(8)));
typedef float f32x4 __attribute__((ext_vector_type(4)));

__device__ __forceinline__ float blo(unsigned u) { return __uint_as_float(u << 16); }
__device__ __forceinline__ float bhi(unsigned u) { return __uint_as_float(u & 0xffff0000u); }
__device__ __forceinline__ unsigned pkbf(float a, float b) {
    unsigned ua = __float_as_uint(a), ub = __float_as_uint(b);
    ua += 0x7fff + ((ua >> 16) & 1);
    ub += 0x7fff + ((ub >> 16) & 1);
    return (ua >> 16) | (ub & 0xffff0000u);
}

// init: cnt=1 (self-loop rank 0) + weight transpose/convert
__global__ void init_kernel(const float* __restrict__ W1, const float* __restrict__ W2,
                            int* __restrict__ cnt, unsigned short* __restrict__ w1t,
                            unsigned short* __restrict__ w2t, int n) {
    int i = blockIdx.x * 256 + threadIdx.x;
    if (i < n) cnt[i] = 1;
    if (i < C1 * FIN) {
        int j = i >> 7, k = i & 127;
        float v = W1[(size_t)k * C1 + j];
        w1t[i] = (unsigned short)(pkbf(v, v) & 0xffffu);
    } else if (i < C1 * FIN + C2 * C1) {
        int j2 = i - C1 * FIN;
        int j = j2 >> 8, k = j2 & 255;
        float v = W2[(size_t)k * C2 + j];
        w2t[j2] = (unsigned short)(pkbf(v, v) & 0xffffu);
    }
}

// 4 real edges/thread: count in-degree AND record each edge's rank (>=1).
__global__ void hist_kernel(const int* __restrict__ ei, int E, int T,
                            int* cnt, int* __restrict__ offs) {
    int base = blockIdx.x * 256 + threadIdx.x;
    if (base >= T) return;
    int d[4], o[4];
    #pragma unroll
    for (int i = 0; i < 4; ++i) {
        int e = base + i * T;
        d[i] = (e < E) ? ei[E + e] : -1;
    }
    #pragma unroll
    for (int i = 0; i < 4; ++i)
        if (d[i] >= 0) o[i] = atomicAdd(&cnt[d[i]], 1);
    #pragma unroll
    for (int i = 0; i < 4; ++i)
        if (d[i] >= 0) offs[base + i * T] = o[i];
}

__global__ void scan1_kernel(const int* __restrict__ cnt, int n,
                             int* __restrict__ pref, int* __restrict__ bsum) {
    int tid = threadIdx.x, lane = tid & 63, w = tid >> 6;
    int i = blockIdx.x * 256 + tid;
    int v = (i < n) ? cnt[i] : 0;
    int sc = v;
    #pragma unroll
    for (int d = 1; d < 64; d <<= 1) {
        int t = __shfl_up(sc, d, 64);
        if (lane >= d) sc += t;
    }
    __shared__ int ws[4];
    if (lane == 63) ws[w] = sc;
    __syncthreads();
    int woff = 0;
    #pragma unroll
    for (int k = 0; k < 4; ++k) woff += (k < w) ? ws[k] : 0;
    if (i < n) pref[i] = woff + sc - v;
    if (tid == 255) bsum[blockIdx.x] = woff + sc;
}

__global__ void scan2_kernel(int* bsum, int nb) {
    int tid = threadIdx.x, lane = tid & 63, w = tid >> 6;
    int v = (tid < nb) ? bsum[tid] : 0;
    int sc = v;
    #pragma unroll
    for (int d = 1; d < 64; d <<= 1) {
        int t = __shfl_up(sc, d, 64);
        if (lane >= d) sc += t;
    }
    __shared__ int ws[4];
    if (lane == 63) ws[w] = sc;
    __syncthreads();
    int woff = 0;
    #pragma unroll
    for (int k = 0; k < 4; ++k) woff += (k < w) ? ws[k] : 0;
    __syncthreads();
    if (tid < nb) bsum[tid] = woff + sc - v;
}

// writes rowptr AND places the self-loop at rank 0 of each segment.
__global__ void scan3_kernel(const int* __restrict__ pref, const int* __restrict__ bsum,
                             int n, int ETOT, int* __restrict__ rowptr,
                             int* __restrict__ colb) {
    int i = blockIdx.x * 256 + threadIdx.x;
    if (i < n) {
        int rp = pref[i] + bsum[blockIdx.x];
        rowptr[i] = rp;
        colb[rp] = i;                  // self loop, rank 0
    }
    if (i == 0) rowptr[n] = ETOT;
}

__global__ void scatter_kernel(const int* __restrict__ ei, const int* __restrict__ rowptr,
                               const int* __restrict__ offs, int E, int T,
                               int* __restrict__ colb) {
    int base = blockIdx.x * 256 + threadIdx.x;
    if (base >= T) return;
    #pragma unroll
    for (int i = 0; i < 4; ++i) {
        int e = base + i * T;
        if (e >= E) continue;
        int src = ei[e], dst = ei[E + e];
        colb[rowptr[dst] + offs[e]] = src;
    }
}

// ---- gemm1: h1[N,256] fp8 = x[N,128](f32, converted in staging) @ w1t^T ----
__global__ __launch_bounds__(256) void gemm1_mfma(
    const float* __restrict__ x, const unsigned short* __restrict__ w1t,
    const float* __restrict__ att_s, const float* __restrict__ att_d,
    unsigned char* __restrict__ h1, float* __restrict__ as1, float* __restrict__ ad1, int Nn) {
    __shared__ __align__(16) unsigned char sA[64 * 256];
    int tid = threadIdx.x;
    int row0 = blockIdx.x * 64;
    #pragma unroll
    for (int rep = 0; rep < 4; ++rep) {
        int flat = rep * 256 + tid;
        int row = flat >> 4, c16 = flat & 15;
        uint4 v = make_uint4(0u, 0u, 0u, 0u);
        if (row0 + row < Nn) {
            const float4* p = reinterpret_cast<const float4*>(
                x + (size_t)(row0 + row) * FIN + c16 * 8);
            float4 f0 = p[0], f1 = p[1];
            v.x = pkbf(f0.x, f0.y); v.y = pkbf(f0.z, f0.w);
            v.z = pkbf(f1.x, f1.y); v.w = pkbf(f1.z, f1.w);
        }
        *reinterpret_cast<uint4*>(sA + ((row * 256 + c16 * 16) ^ ((row & 7) << 4))) = v;
    }
    __syncthreads();
    int w = tid >> 6, l = tid & 63;
    int lr = l & 15, lq = l >> 4;
    int arow = w * 16 + lr;
    bf16x8 a[4];
    #pragma unroll
    for (int ks = 0; ks < 4; ++ks)
        a[ks] = *reinterpret_cast<const bf16x8*>(
            sA + ((arow * 256 + ks * 64 + lq * 16) ^ ((arow & 7) << 4)));
    const unsigned char* wb = reinterpret_cast<const unsigned char*>(w1t);
    float ps[4] = {0.f, 0.f, 0.f, 0.f}, pd[4] = {0.f, 0.f, 0.f, 0.f};
    #pragma unroll
    for (int nt = 0; nt < 16; ++nt) {
        f32x4 acc = {0.f, 0.f, 0.f, 0.f};
        #pragma unroll
        for (int ks = 0; ks < 4; ++ks) {
            bf16x8 b = *reinterpret_cast<const bf16x8*>(
                wb + (size_t)(nt * 16 + lr) * 256 + ks * 64 + lq * 16);
            acc = __builtin_amdgcn_mfma_f32_16x16x32_bf16(a[ks], b, acc, 0, 0, 0);
        }
        int col = nt * 16 + lr;
        float sa = att_s[col], da = att_d[col];
        #pragma unroll
        for (int reg = 0; reg < 4; ++reg) {
            int row = row0 + w * 16 + lq * 4 + reg;
            if (row < Nn) {
                unsigned pk = __builtin_amdgcn_cvt_pk_fp8_f32(acc[reg], acc[reg], 0, false);
                h1[(size_t)row * C1 + col] = (unsigned char)(pk & 0xffu);
            }
            ps[reg] = fmaf(acc[reg], sa, ps[reg]);
            pd[reg] = fmaf(acc[reg], da, pd[reg]);
        }
        if (nt & 1) {
            #pragma unroll
            for (int reg = 0; reg < 4; ++reg) {
                #pragma unroll
                for (int mk = 8; mk >= 1; mk >>= 1) {
                    ps[reg] += __shfl_xor(ps[reg], mk, 64);
                    pd[reg] += __shfl_xor(pd[reg], mk, 64);
                }
            }
            if (lr == 0) {
                int hh = nt >> 1;
                #pragma unroll
                for (int reg = 0; reg < 4; ++reg) {
                    int row = row0 + w * 16 + lq * 4 + reg;
                    if (row < Nn) {
                        as1[row * NH + hh] = ps[reg];
                        ad1[row * NH + hh] = pd[reg];
                    }
                }
            }
            #pragma unroll
            for (int reg = 0; reg < 4; ++reg) { ps[reg] = 0.f; pd[reg] = 0.f; }
        }
    }
}

// Layer-1 aggregation: 1 wave/node, 2 nodes/block, 2 edges/iter (R11 form).
__global__ __launch_bounds__(128) void agg1_kernel(
    const int* __restrict__ rowptr, const int* __restrict__ colb,
    const float* __restrict__ as1, const float* __restrict__ ad1,
    const unsigned char* __restrict__ h1, const float* __restrict__ b1,
    __hip_bfloat16* __restrict__ x1e, int N) {
    int wid = threadIdx.x >> 6, lane = threadIdx.x & 63;
    int n = blockIdx.x * 2 + wid;
    __shared__ float sp[2][CH1 * 9];
    __shared__ int soff[2][CH1];
    __shared__ float advs[2][NH];
    if (n >= N) return;
    int start = rowptr[n], end = rowptr[n + 1];
    int h = lane >> 3, sub = lane & 7;
    int half = lane >> 5, l5 = lane & 31;
    int hq = l5 >> 2;
    soff[wid][lane] = 0;
    if (lane < NH) advs[wid][lane] = ad1[n * NH + lane];
    float adr[NH];
    #pragma unroll
    for (int hh = 0; hh < NH; ++hh) adr[hh] = advs[wid][hh];

    float m = -INFINITY, denom = 0.f;
    floatx2 A01 = {0.f, 0.f}, A23 = {0.f, 0.f}, A45 = {0.f, 0.f}, A67 = {0.f, 0.f};
    for (int base = start; base < end; base += CH1) {
        int cn = min(CH1, end - base);
        if (lane < cn) {
            int s = colb[base + lane];
            soff[wid][lane] = s << 8;
            const float4* ap = reinterpret_cast<const float4*>(as1 + (size_t)s * NH);
            float4 q0 = ap[0], q1 = ap[1];
            float av[8] = {q0.x, q0.y, q0.z, q0.w, q1.x, q1.y, q1.z, q1.w};
            #pragma unroll
            for (int hh = 0; hh < NH; ++hh) {
                float e = av[hh] + adr[hh];
                e = e > 0.f ? e : 0.2f * e;
                sp[wid][lane * 9 + hh] = e;
            }
        }
        float cmax = -INFINITY;
        for (int e = sub; e < cn; e += 8) cmax = fmaxf(cmax, sp[wid][e * 9 + h]);
        #pragma unroll
        for (int mk = 4; mk >= 1; mk >>= 1) cmax = fmaxf(cmax, __shfl_xor(cmax, mk, 64));
        float newm = fmaxf(m, cmax);
        float scale = __expf(m - newm);
        float scale_g = __shfl(scale, hq << 3, 64);
        floatx2 s2 = {scale_g, scale_g};
        A01 *= s2; A23 *= s2; A45 *= s2; A67 *= s2;
        denom *= scale; m = newm;
        float psum = 0.f;
        for (int e = sub; e < cn; e += 8) {
            float p = __expf(sp[wid][e * 9 + h] - m);
            sp[wid][e * 9 + h] = p;
            psum += p;
        }
        #pragma unroll
        for (int mk = 4; mk >= 1; mk >>= 1) psum += __shfl_xor(psum, mk, 64);
        denom += psum;
        #pragma unroll 2
        for (int e2 = 0; e2 < cn; e2 += 2) {
            int e = e2 + half;
            bool ok = e < cn;
            int off = soff[wid][ok ? e : 0];
            float p = ok ? sp[wid][e * 9 + hq] : 0.f;
            floatx2 p2 = {p, p};
            uint2 u = *reinterpret_cast<const uint2*>(h1 + off + l5 * 8);
            floatx2 f01 = __builtin_amdgcn_cvt_pk_f32_fp8((int)u.x, false);
            floatx2 f23 = __builtin_amdgcn_cvt_pk_f32_fp8((int)u.x, true);
            floatx2 f45 = __builtin_amdgcn_cvt_pk_f32_fp8((int)u.y, false);
            floatx2 f67 = __builtin_amdgcn_cvt_pk_f32_fp8((int)u.y, true);
            A01 = __builtin_elementwise_fma(p2, f01, A01);
            A23 = __builtin_elementwise_fma(p2, f23, A23);
            A45 = __builtin_elementwise_fma(p2, f45, A45);
            A67 = __builtin_elementwise_fma(p2, f67, A67);
        }
    }
    float a0 = A01.x, a1 = A01.y, a2 = A23.x, a3 = A23.y;
    float a4 = A45.x, a5 = A45.y, a6 = A67.x, a7 = A67.y;
    a0 += __shfl_xor(a0, 32, 64); a1 += __shfl_xor(a1, 32, 64);
    a2 += __shfl_xor(a2, 32, 64); a3 += __shfl_xor(a3, 32, 64);
    a4 += __shfl_xor(a4, 32, 64); a5 += __shfl_xor(a5, 32, 64);
    a6 += __shfl_xor(a6, 32, 64); a7 += __shfl_xor(a7, 32, 64);
    float invd = 1.f / __shfl(denom, hq << 3, 64);
    if (half == 0) {
        const float4* bp = reinterpret_cast<const float4*>(b1 + l5 * 8);
        float4 bv0 = bp[0], bv1 = bp[1];
        float v0 = a0 * invd + bv0.x, v1 = a1 * invd + bv0.y;
        float v2 = a2 * invd + bv0.z, v3 = a3 * invd + bv0.w;
        float v4 = a4 * invd + bv1.x, v5 = a5 * invd + bv1.y;
        float v6 = a6 * invd + bv1.z, v7 = a7 * invd + bv1.w;
        v0 = v0 > 0.f ? v0 : __expf(v0) - 1.f;
        v1 = v1 > 0.f ? v1 : __expf(v1) - 1.f;
        v2 = v2 > 0.f ? v2 : __expf(v2) - 1.f;
        v3 = v3 > 0.f ? v3 : __expf(v3) - 1.f;
        v4 = v4 > 0.f ? v4 : __expf(v4) - 1.f;
        v5 = v5 > 0.f ? v5 : __expf(v5) - 1.f;
        v6 = v6 > 0.f ? v6 : __expf(v6) - 1.f;
        v7 = v7 > 0.f ? v7 : __expf(v7) - 1.f;
        uint4 w;
        w.x = pkbf(v0, v1); w.y = pkbf(v2, v3);
        w.z = pkbf(v4, v5); w.w = pkbf(v6, v7);
        *reinterpret_cast<uint4*>(x1e + (size_t)n * C1 + l5 * 8) = w;
    }
}

// ---- gemm2: h2[N,64] fp8 = x1e[N,256] @ w2t^T + as2/ad2 epilogue ----
__global__ __launch_bounds__(256) void gemm2_mfma(
    const unsigned short* __restrict__ x1e, const unsigned short* __restrict__ w2t,
    const float* __restrict__ att_s2, const float* __restrict__ att_d2,
    unsigned char* __restrict__ h2, float* __restrict__ as2, float* __restrict__ ad2, int Nn) {
    __shared__ __align__(16) unsigned char sA[64 * 512];
    int tid = threadIdx.x;
    int row0 = blockIdx.x * 64;
    #pragma unroll
    for (int rep = 0; rep < 8; ++rep) {
        int flat = rep * 256 + tid;
        int row = flat >> 5, c16 = flat & 31;
        uint4 v = make_uint4(0u, 0u, 0u, 0u);
        if (row0 + row < Nn)
            v = *reinterpret_cast<const uint4*>(
                reinterpret_cast<const unsigned char*>(x1e) + (size_t)(row0 + row) * 512 + c16 * 16);
        *reinterpret_cast<uint4*>(sA + ((row * 512 + c16 * 16) ^ ((row & 7) << 4))) = v;
    }
    __syncthreads();
    int w = tid >> 6, l = tid & 63;
    int lr = l & 15, lq = l >> 4;
    int arow = w * 16 + lr;
    bf16x8 a[8];
    #pragma unroll
    for (int ks = 0; ks < 8; ++ks)
        a[ks] = *reinterpret_cast<const bf16x8*>(
            sA + ((arow * 512 + ks * 64 + lq * 16) ^ ((arow & 7) << 4)));
    const unsigned char* wb = reinterpret_cast<const unsigned char*>(w2t);
    float ps[4] = {0.f, 0.f, 0.f, 0.f}, pd[4] = {0.f, 0.f, 0.f, 0.f};
    #pragma unroll
    for (int nt = 0; nt < 4; ++nt) {
        f32x4 acc = {0.f, 0.f, 0.f, 0.f};
        #pragma unroll
        for (int ks = 0; ks < 8; ++ks) {
            bf16x8 b = *reinterpret_cast<const bf16x8*>(
                wb + (size_t)(nt * 16 + lr) * 512 + ks * 64 + lq * 16);
            acc = __builtin_amdgcn_mfma_f32_16x16x32_bf16(a[ks], b, acc, 0, 0, 0);
        }
        int col = nt * 16 + lr;
        float sa = att_s2[col], da = att_d2[col];
        #pragma unroll
        for (int reg = 0; reg < 4; ++reg) {
            int row = row0 + w * 16 + lq * 4 + reg;
            if (row < Nn) {
                unsigned pk = __builtin_amdgcn_cvt_pk_fp8_f32(acc[reg], acc[reg], 0, false);
                h2[(size_t)row * C2 + col] = (unsigned char)(pk & 0xffu);
            }
            ps[reg] = fmaf(acc[reg], sa, ps[reg]);
            pd[reg] = fmaf(acc[reg], da, pd[reg]);
        }
    }
    #pragma unroll
    for (int reg = 0; reg < 4; ++reg) {
        #pragma unroll
        for (int mk = 8; mk >= 1; mk >>= 1) {
            ps[reg] += __shfl_xor(ps[reg], mk, 64);
            pd[reg] += __shfl_xor(pd[reg], mk, 64);
        }
    }
    if (lr == 0) {
        #pragma unroll
        for (int reg = 0; reg < 4; ++reg) {
            int row = row0 + w * 16 + lq * 4 + reg;
            if (row < Nn) { as2[row] = ps[reg]; ad2[row] = pd[reg]; }
        }
    }
}

// Layer-2 aggregation + bias + log_softmax. 1 wave/node, 2 nodes/block.
// h2 fp8: 64B rows, 16 lanes/edge x 4B, 4 edges/iter.
__global__ __launch_bounds__(128) void agg2_kernel(
    const int* __restrict__ rowptr, const int* __restrict__ colb,
    const float* __restrict__ as2, const float* __restrict__ ad2,
    const unsigned char* __restrict__ h2, const float* __restrict__ b2,
    float* __restrict__ out, int N) {
    int wid = threadIdx.x >> 6, lane = threadIdx.x & 63;
    int n = blockIdx.x * 2 + wid;
    __shared__ float sp2[2][64];
    __shared__ int soff2[2][64];
    if (n >= N) return;
    int start = rowptr[n], end = rowptr[n + 1];
    int q = lane >> 4, l4 = lane & 15;
    soff2[wid][lane] = 0;
    float adn = ad2[n];
    float m = -INFINITY, denom = 0.f;
    floatx2 A01 = {0.f, 0.f}, A23 = {0.f, 0.f};
    for (int base = start; base < end; base += 64) {
        int cn = min(64, end - base);
        float logit = -INFINITY;
        if (lane < cn) {
            int s = colb[base + lane];
            soff2[wid][lane] = s << 6;     // byte offset into fp8 h2 (64B rows)
            float e = as2[s] + adn;
            logit = e > 0.f ? e : 0.2f * e;
        }
        float cmax = logit;
        #pragma unroll
        for (int mk = 32; mk >= 1; mk >>= 1) cmax = fmaxf(cmax, __shfl_xor(cmax, mk, 64));
        float newm = fmaxf(m, cmax);
        float scale = __expf(m - newm);
        floatx2 s2 = {scale, scale};
        A01 *= s2; A23 *= s2;
        denom *= scale; m = newm;
        float p = (lane < cn) ? __expf(logit - m) : 0.f;
        sp2[wid][lane] = p;
        float psum = p;
        #pragma unroll
        for (int mk = 32; mk >= 1; mk >>= 1) psum += __shfl_xor(psum, mk, 64);
        denom += psum;
        #pragma unroll 2
        for (int e2 = 0; e2 < cn; e2 += 4) {
            int e = e2 + q;
            bool ok = e < cn;
            int off = soff2[wid][ok ? e : 0];
            float pe = ok ? sp2[wid][e] : 0.f;
            floatx2 p2 = {pe, pe};
            unsigned u = *reinterpret_cast<const unsigned*>(h2 + off + l4 * 4);
            floatx2 f01 = __builtin_amdgcn_cvt_pk_f32_fp8((int)u, false);
            floatx2 f23 = __builtin_amdgcn_cvt_pk_f32_fp8((int)u, true);
            A01 = __builtin_elementwise_fma(p2, f01, A01);
            A23 = __builtin_elementwise_fma(p2, f23, A23);
        }
    }
    float a0 = A01.x, a1 = A01.y, a2 = A23.x, a3 = A23.y;
    a0 += __shfl_xor(a0, 16, 64); a1 += __shfl_xor(a1, 16, 64);
    a2 += __shfl_xor(a2, 16, 64); a3 += __shfl_xor(a3, 16, 64);
    a0 += __shfl_xor(a0, 32, 64); a1 += __shfl_xor(a1, 32, 64);
    a2 += __shfl_xor(a2, 32, 64); a3 += __shfl_xor(a3, 32, 64);
    float invd = 1.f / denom;
    const float4* bp = reinterpret_cast<const float4*>(b2 + l4 * 4);
    float4 bv = bp[0];
    float v0 = a0 * invd + bv.x, v1 = a1 * invd + bv.y;
    float v2 = a2 * invd + bv.z, v3 = a3 * invd + bv.w;
    float mx = fmaxf(fmaxf(v0, v1), fmaxf(v2, v3));
    #pragma unroll
    for (int mk = 8; mk >= 1; mk >>= 1) mx = fmaxf(mx, __shfl_xor(mx, mk, 64));
    float sum = __expf(v0 - mx) + __expf(v1 - mx) + __expf(v2 - mx) + __expf(v3 - mx);
    #pragma unroll
    for (int mk = 8; mk >= 1; mk >>= 1) sum += __shfl_xor(sum, mk, 64);
    float ls = logf(sum);
    if (q == 0) {
        float4 o = make_float4(v0 - mx - ls, v1 - mx - ls, v2 - mx - ls, v3 - mx - ls);
        *reinterpret_cast<float4*>(out + (size_t)n * C2 + l4 * 4) = o;
    }
}

extern "C" void kernel_launch(void* const* d_in, const int* in_sizes, int n_in,
                              void* d_out, int out_size, void* d_ws, size_t ws_size,
                              hipStream_t stream) {
    const float* x      = (const float*)d_in[0];
    const int*   ei     = (const int*)d_in[1];
    const float* W1     = (const float*)d_in[2];
    const float* att_s1 = (const float*)d_in[3];
    const float* att_d1 = (const float*)d_in[4];
    const float* b1     = (const float*)d_in[5];
    const float* W2     = (const float*)d_in[6];
    const float* att_s2 = (const float*)d_in[7];
    const float* att_d2 = (const float*)d_in[8];
    const float* b2     = (const float*)d_in[9];
    float* out = (float*)d_out;

    const int N = out_size / C2;          // 50000
    const int E = in_sizes[1] / 2;        // 1.6M
    const int ETOT = E + N;
    const int NB = (N + 255) / 256;

    char* ws = (char*)d_ws;
    size_t off = 0;
    auto alloc = [&](size_t bytes) -> void* {
        void* p = ws + off;
        off += (bytes + 255) & ~(size_t)255;
        return p;
    };
    unsigned char* h1 = (unsigned char*)alloc((size_t)N * C1);           // 12.8 MB fp8
    __hip_bfloat16* x1e = (__hip_bfloat16*)alloc((size_t)N * C1 * 2);    // 25.6 MB bf16
    unsigned short* w1t = (unsigned short*)alloc((size_t)C1 * FIN * 2);
    unsigned short* w2t = (unsigned short*)alloc((size_t)C2 * C1 * 2);
    float* as1  = (float*)alloc((size_t)N * NH * 4);
    float* ad1  = (float*)alloc((size_t)N * NH * 4);
    float* as2  = (float*)alloc((size_t)N * 4);
    float* ad2  = (float*)alloc((size_t)N * 4);
    int*   cnt    = (int*)alloc((size_t)N * 4);
    int*   rowptr = (int*)alloc((size_t)(N + 1) * 4);
    int*   pref   = (int*)alloc((size_t)N * 4);
    int*   bsum   = (int*)alloc((size_t)NB * 4);
    int*   offs   = (int*)alloc((size_t)E * 4);
    int*   colb   = (int*)alloc((size_t)ETOT * 4);
    unsigned char* h2 = h1;   // reuse after agg1 (3.2MB <= 12.8MB)

    // --- CSR build (self-loops prefilled at rank 0 via scan3) + init ---
    const int T = (E + 3) / 4;
    init_kernel<<<(N + 255) / 256, 256, 0, stream>>>(W1, W2, cnt, w1t, w2t, N);
    hist_kernel<<<(T + 255) / 256, 256, 0, stream>>>(ei, E, T, cnt, offs);
    scan1_kernel<<<NB, 256, 0, stream>>>(cnt, N, pref, bsum);
    scan2_kernel<<<1, 256, 0, stream>>>(bsum, NB);
    scan3_kernel<<<NB, 256, 0, stream>>>(pref, bsum, N, ETOT, rowptr, colb);
    scatter_kernel<<<(T + 255) / 256, 256, 0, stream>>>(ei, rowptr, offs, E, T, colb);

    // --- Layer 1 ---
    gemm1_mfma<<<(N + 63) / 64, 256, 0, stream>>>(x, w1t, att_s1, att_d1, h1, as1, ad1, N);
    agg1_kernel<<<(N + 1) / 2, 128, 0, stream>>>(rowptr, colb, as1, ad1, h1, b1, x1e, N);

    // --- Layer 2 ---
    gemm2_mfma<<<(N + 63) / 64, 256, 0, stream>>>((const unsigned short*)x1e, w2t,
                                                  att_s2, att_d2, h2, as2, ad2, N);
    agg2_kernel<<<(N + 1) / 2, 128, 0, stream>>>(rowptr, colb, as2, ad2, h2, b2, out, N);
}

// Round 15
// 258.288 us; speedup vs baseline: 1.2333x; 1.0676x over previous
//
#include <hip/hip_runtime.h>
#include <hip/hip_bf16.h>
#include <math.h>

// GAT 2-layer forward for MI355X.
// R15 = R14 + (a) scatter fused with gemm1 (independent work, complementary
// pipes: latency-bound scatter hides under MFMA gemm1; same-stream kernels
// can't overlap otherwise), (b) agg1/agg2 at 1 node per 64-thread block
// (kills remaining degree-variance convoy).

#define FIN 128
#define C1 256   // H*D layer1
#define NH 8
#define HD 32
#define C2 64    // F_out
#define CH1 64

typedef float floatx2 __attribute__((ext_vector_type(2)));
typedef short bf16x8 __attribute__((ext_vector_type(8)));
typedef float f32x4 __attribute__((ext_vector_type(4)));

__device__ __forceinline__ float blo(unsigned u) { return __uint_as_float(u << 16); }
__device__ __forceinline__ float bhi(unsigned u) { return __uint_as_float(u & 0xffff0000u); }
__device__ __forceinline__ unsigned pkbf(float a, float b) {
    unsigned ua = __float_as_uint(a), ub = __float_as_uint(b);
    ua += 0x7fff + ((ua >> 16) & 1);
    ub += 0x7fff + ((ub >> 16) & 1);
    return (ua >> 16) | (ub & 0xffff0000u);
}

// init: cnt=1 (self-loop rank 0) + weight transpose/convert
__global__ void init_kernel(const float* __restrict__ W1, const float* __restrict__ W2,
                            int* __restrict__ cnt, unsigned short* __restrict__ w1t,
                            unsigned short* __restrict__ w2t, int n) {
    int i = blockIdx.x * 256 + threadIdx.x;
    if (i < n) cnt[i] = 1;
    if (i < C1 * FIN) {
        int j = i >> 7, k = i & 127;
        float v = W1[(size_t)k * C1 + j];
        w1t[i] = (unsigned short)(pkbf(v, v) & 0xffffu);
    } else if (i < C1 * FIN + C2 * C1) {
        int j2 = i - C1 * FIN;
        int j = j2 >> 8, k = j2 & 255;
        float v = W2[(size_t)k * C2 + j];
        w2t[j2] = (unsigned short)(pkbf(v, v) & 0xffffu);
    }
}

// 4 real edges/thread: count in-degree AND record each edge's rank (>=1).
__global__ void hist_kernel(const int* __restrict__ ei, int E, int T,
                            int* cnt, int* __restrict__ offs) {
    int base = blockIdx.x * 256 + threadIdx.x;
    if (base >= T) return;
    int d[4], o[4];
    #pragma unroll
    for (int i = 0; i < 4; ++i) {
        int e = base + i * T;
        d[i] = (e < E) ? ei[E + e] : -1;
    }
    #pragma unroll
    for (int i = 0; i < 4; ++i)
        if (d[i] >= 0) o[i] = atomicAdd(&cnt[d[i]], 1);
    #pragma unroll
    for (int i = 0; i < 4; ++i)
        if (d[i] >= 0) offs[base + i * T] = o[i];
}

__global__ void scan1_kernel(const int* __restrict__ cnt, int n,
                             int* __restrict__ pref, int* __restrict__ bsum) {
    int tid = threadIdx.x, lane = tid & 63, w = tid >> 6;
    int i = blockIdx.x * 256 + tid;
    int v = (i < n) ? cnt[i] : 0;
    int sc = v;
    #pragma unroll
    for (int d = 1; d < 64; d <<= 1) {
        int t = __shfl_up(sc, d, 64);
        if (lane >= d) sc += t;
    }
    __shared__ int ws[4];
    if (lane == 63) ws[w] = sc;
    __syncthreads();
    int woff = 0;
    #pragma unroll
    for (int k = 0; k < 4; ++k) woff += (k < w) ? ws[k] : 0;
    if (i < n) pref[i] = woff + sc - v;
    if (tid == 255) bsum[blockIdx.x] = woff + sc;
}

__global__ void scan2_kernel(int* bsum, int nb) {
    int tid = threadIdx.x, lane = tid & 63, w = tid >> 6;
    int v = (tid < nb) ? bsum[tid] : 0;
    int sc = v;
    #pragma unroll
    for (int d = 1; d < 64; d <<= 1) {
        int t = __shfl_up(sc, d, 64);
        if (lane >= d) sc += t;
    }
    __shared__ int ws[4];
    if (lane == 63) ws[w] = sc;
    __syncthreads();
    int woff = 0;
    #pragma unroll
    for (int k = 0; k < 4; ++k) woff += (k < w) ? ws[k] : 0;
    __syncthreads();
    if (tid < nb) bsum[tid] = woff + sc - v;
}

// writes rowptr AND places the self-loop at rank 0 of each segment.
__global__ void scan3_kernel(const int* __restrict__ pref, const int* __restrict__ bsum,
                             int n, int ETOT, int* __restrict__ rowptr,
                             int* __restrict__ colb) {
    int i = blockIdx.x * 256 + threadIdx.x;
    if (i < n) {
        int rp = pref[i] + bsum[blockIdx.x];
        rowptr[i] = rp;
        colb[rp] = i;                  // self loop, rank 0
    }
    if (i == 0) rowptr[n] = ETOT;
}

// ---- FUSED: blocks [0, GB1) run gemm1 (MFMA); blocks [GB1, ...) run scatter.
// Independent work co-scheduled on the CUs: scatter's store latency hides
// under gemm1's MFMA/LDS work.
__global__ __launch_bounds__(256) void gemm1_scatter_fused(
    const float* __restrict__ x, const unsigned short* __restrict__ w1t,
    const float* __restrict__ att_s, const float* __restrict__ att_d,
    unsigned char* __restrict__ h1, float* __restrict__ as1, float* __restrict__ ad1,
    int Nn, int GB1,
    const int* __restrict__ ei, const int* __restrict__ rowptr,
    const int* __restrict__ offs, int E, int T, int* __restrict__ colb) {
    __shared__ __align__(16) unsigned char sA[64 * 256];
    int tid = threadIdx.x;
    if (blockIdx.x >= GB1) {
        // ---- scatter body ----
        int base = (blockIdx.x - GB1) * 256 + tid;
        if (base >= T) return;
        #pragma unroll
        for (int i = 0; i < 4; ++i) {
            int e = base + i * T;
            if (e >= E) continue;
            int src = ei[e], dst = ei[E + e];
            colb[rowptr[dst] + offs[e]] = src;
        }
        return;
    }
    // ---- gemm1 body ----
    int row0 = blockIdx.x * 64;
    #pragma unroll
    for (int rep = 0; rep < 4; ++rep) {
        int flat = rep * 256 + tid;
        int row = flat >> 4, c16 = flat & 15;
        uint4 v = make_uint4(0u, 0u, 0u, 0u);
        if (row0 + row < Nn) {
            const float4* p = reinterpret_cast<const float4*>(
                x + (size_t)(row0 + row) * FIN + c16 * 8);
            float4 f0 = p[0], f1 = p[1];
            v.x = pkbf(f0.x, f0.y); v.y = pkbf(f0.z, f0.w);
            v.z = pkbf(f1.x, f1.y); v.w = pkbf(f1.z, f1.w);
        }
        *reinterpret_cast<uint4*>(sA + ((row * 256 + c16 * 16) ^ ((row & 7) << 4))) = v;
    }
    __syncthreads();
    int w = tid >> 6, l = tid & 63;
    int lr = l & 15, lq = l >> 4;
    int arow = w * 16 + lr;
    bf16x8 a[4];
    #pragma unroll
    for (int ks = 0; ks < 4; ++ks)
        a[ks] = *reinterpret_cast<const bf16x8*>(
            sA + ((arow * 256 + ks * 64 + lq * 16) ^ ((arow & 7) << 4)));
    const unsigned char* wb = reinterpret_cast<const unsigned char*>(w1t);
    float ps[4] = {0.f, 0.f, 0.f, 0.f}, pd[4] = {0.f, 0.f, 0.f, 0.f};
    #pragma unroll
    for (int nt = 0; nt < 16; ++nt) {
        f32x4 acc = {0.f, 0.f, 0.f, 0.f};
        #pragma unroll
        for (int ks = 0; ks < 4; ++ks) {
            bf16x8 b = *reinterpret_cast<const bf16x8*>(
                wb + (size_t)(nt * 16 + lr) * 256 + ks * 64 + lq * 16);
            acc = __builtin_amdgcn_mfma_f32_16x16x32_bf16(a[ks], b, acc, 0, 0, 0);
        }
        int col = nt * 16 + lr;
        float sa = att_s[col], da = att_d[col];
        #pragma unroll
        for (int reg = 0; reg < 4; ++reg) {
            int row = row0 + w * 16 + lq * 4 + reg;
            if (row < Nn) {
                unsigned pk = __builtin_amdgcn_cvt_pk_fp8_f32(acc[reg], acc[reg], 0, false);
                h1[(size_t)row * C1 + col] = (unsigned char)(pk & 0xffu);
            }
            ps[reg] = fmaf(acc[reg], sa, ps[reg]);
            pd[reg] = fmaf(acc[reg], da, pd[reg]);
        }
        if (nt & 1) {
            #pragma unroll
            for (int reg = 0; reg < 4; ++reg) {
                #pragma unroll
                for (int mk = 8; mk >= 1; mk >>= 1) {
                    ps[reg] += __shfl_xor(ps[reg], mk, 64);
                    pd[reg] += __shfl_xor(pd[reg], mk, 64);
                }
            }
            if (lr == 0) {
                int hh = nt >> 1;
                #pragma unroll
                for (int reg = 0; reg < 4; ++reg) {
                    int row = row0 + w * 16 + lq * 4 + reg;
                    if (row < Nn) {
                        as1[row * NH + hh] = ps[reg];
                        ad1[row * NH + hh] = pd[reg];
                    }
                }
            }
            #pragma unroll
            for (int reg = 0; reg < 4; ++reg) { ps[reg] = 0.f; pd[reg] = 0.f; }
        }
    }
}

// Layer-1 aggregation: 1 node per 64-thread block (1 wave).
__global__ __launch_bounds__(64) void agg1_kernel(
    const int* __restrict__ rowptr, const int* __restrict__ colb,
    const float* __restrict__ as1, const float* __restrict__ ad1,
    const unsigned char* __restrict__ h1, const float* __restrict__ b1,
    __hip_bfloat16* __restrict__ x1e, int N) {
    int lane = threadIdx.x;
    int n = blockIdx.x;
    __shared__ float sp[CH1 * 9];
    __shared__ int soff[CH1];
    __shared__ float advs[NH];
    int start = rowptr[n], end = rowptr[n + 1];
    int h = lane >> 3, sub = lane & 7;
    int half = lane >> 5, l5 = lane & 31;
    int hq = l5 >> 2;
    soff[lane] = 0;
    if (lane < NH) advs[lane] = ad1[n * NH + lane];
    float adr[NH];
    #pragma unroll
    for (int hh = 0; hh < NH; ++hh) adr[hh] = advs[hh];

    float m = -INFINITY, denom = 0.f;
    floatx2 A01 = {0.f, 0.f}, A23 = {0.f, 0.f}, A45 = {0.f, 0.f}, A67 = {0.f, 0.f};
    for (int base = start; base < end; base += CH1) {
        int cn = min(CH1, end - base);
        if (lane < cn) {
            int s = colb[base + lane];
            soff[lane] = s << 8;
            const float4* ap = reinterpret_cast<const float4*>(as1 + (size_t)s * NH);
            float4 q0 = ap[0], q1 = ap[1];
            float av[8] = {q0.x, q0.y, q0.z, q0.w, q1.x, q1.y, q1.z, q1.w};
            #pragma unroll
            for (int hh = 0; hh < NH; ++hh) {
                float e = av[hh] + adr[hh];
                e = e > 0.f ? e : 0.2f * e;
                sp[lane * 9 + hh] = e;
            }
        }
        float cmax = -INFINITY;
        for (int e = sub; e < cn; e += 8) cmax = fmaxf(cmax, sp[e * 9 + h]);
        #pragma unroll
        for (int mk = 4; mk >= 1; mk >>= 1) cmax = fmaxf(cmax, __shfl_xor(cmax, mk, 64));
        float newm = fmaxf(m, cmax);
        float scale = __expf(m - newm);
        float scale_g = __shfl(scale, hq << 3, 64);
        floatx2 s2 = {scale_g, scale_g};
        A01 *= s2; A23 *= s2; A45 *= s2; A67 *= s2;
        denom *= scale; m = newm;
        float psum = 0.f;
        for (int e = sub; e < cn; e += 8) {
            float p = __expf(sp[e * 9 + h] - m);
            sp[e * 9 + h] = p;
            psum += p;
        }
        #pragma unroll
        for (int mk = 4; mk >= 1; mk >>= 1) psum += __shfl_xor(psum, mk, 64);
        denom += psum;
        #pragma unroll 2
        for (int e2 = 0; e2 < cn; e2 += 2) {
            int e = e2 + half;
            bool ok = e < cn;
            int off = soff[ok ? e : 0];
            float p = ok ? sp[e * 9 + hq] : 0.f;
            floatx2 p2 = {p, p};
            uint2 u = *reinterpret_cast<const uint2*>(h1 + off + l5 * 8);
            floatx2 f01 = __builtin_amdgcn_cvt_pk_f32_fp8((int)u.x, false);
            floatx2 f23 = __builtin_amdgcn_cvt_pk_f32_fp8((int)u.x, true);
            floatx2 f45 = __builtin_amdgcn_cvt_pk_f32_fp8((int)u.y, false);
            floatx2 f67 = __builtin_amdgcn_cvt_pk_f32_fp8((int)u.y, true);
            A01 = __builtin_elementwise_fma(p2, f01, A01);
            A23 = __builtin_elementwise_fma(p2, f23, A23);
            A45 = __builtin_elementwise_fma(p2, f45, A45);
            A67 = __builtin_elementwise_fma(p2, f67, A67);
        }
    }
    float a0 = A01.x, a1 = A01.y, a2 = A23.x, a3 = A23.y;
    float a4 = A45.x, a5 = A45.y, a6 = A67.x, a7 = A67.y;
    a0 += __shfl_xor(a0, 32, 64); a1 += __shfl_xor(a1, 32, 64);
    a2 += __shfl_xor(a2, 32, 64); a3 += __shfl_xor(a3, 32, 64);
    a4 += __shfl_xor(a4, 32, 64); a5 += __shfl_xor(a5, 32, 64);
    a6 += __shfl_xor(a6, 32, 64); a7 += __shfl_xor(a7, 32, 64);
    float invd = 1.f / __shfl(denom, hq << 3, 64);
    if (half == 0) {
        const float4* bp = reinterpret_cast<const float4*>(b1 + l5 * 8);
        float4 bv0 = bp[0], bv1 = bp[1];
        float v0 = a0 * invd + bv0.x, v1 = a1 * invd + bv0.y;
        float v2 = a2 * invd + bv0.z, v3 = a3 * invd + bv0.w;
        float v4 = a4 * invd + bv1.x, v5 = a5 * invd + bv1.y;
        float v6 = a6 * invd + bv1.z, v7 = a7 * invd + bv1.w;
        v0 = v0 > 0.f ? v0 : __expf(v0) - 1.f;
        v1 = v1 > 0.f ? v1 : __expf(v1) - 1.f;
        v2 = v2 > 0.f ? v2 : __expf(v2) - 1.f;
        v3 = v3 > 0.f ? v3 : __expf(v3) - 1.f;
        v4 = v4 > 0.f ? v4 : __expf(v4) - 1.f;
        v5 = v5 > 0.f ? v5 : __expf(v5) - 1.f;
        v6 = v6 > 0.f ? v6 : __expf(v6) - 1.f;
        v7 = v7 > 0.f ? v7 : __expf(v7) - 1.f;
        uint4 w;
        w.x = pkbf(v0, v1); w.y = pkbf(v2, v3);
        w.z = pkbf(v4, v5); w.w = pkbf(v6, v7);
        *reinterpret_cast<uint4*>(x1e + (size_t)n * C1 + l5 * 8) = w;
    }
}

// ---- gemm2: h2[N,64] fp8 = x1e[N,256] @ w2t^T + as2/ad2 epilogue ----
__global__ __launch_bounds__(256) void gemm2_mfma(
    const unsigned short* __restrict__ x1e, const unsigned short* __restrict__ w2t,
    const float* __restrict__ att_s2, const float* __restrict__ att_d2,
    unsigned char* __restrict__ h2, float* __restrict__ as2, float* __restrict__ ad2, int Nn) {
    __shared__ __align__(16) unsigned char sA[64 * 512];
    int tid = threadIdx.x;
    int row0 = blockIdx.x * 64;
    #pragma unroll
    for (int rep = 0; rep < 8; ++rep) {
        int flat = rep * 256 + tid;
        int row = flat >> 5, c16 = flat & 31;
        uint4 v = make_uint4(0u, 0u, 0u, 0u);
        if (row0 + row < Nn)
            v = *reinterpret_cast<const uint4*>(
                reinterpret_cast<const unsigned char*>(x1e) + (size_t)(row0 + row) * 512 + c16 * 16);
        *reinterpret_cast<uint4*>(sA + ((row * 512 + c16 * 16) ^ ((row & 7) << 4))) = v;
    }
    __syncthreads();
    int w = tid >> 6, l = tid & 63;
    int lr = l & 15, lq = l >> 4;
    int arow = w * 16 + lr;
    bf16x8 a[8];
    #pragma unroll
    for (int ks = 0; ks < 8; ++ks)
        a[ks] = *reinterpret_cast<const bf16x8*>(
            sA + ((arow * 512 + ks * 64 + lq * 16) ^ ((arow & 7) << 4)));
    const unsigned char* wb = reinterpret_cast<const unsigned char*>(w2t);
    float ps[4] = {0.f, 0.f, 0.f, 0.f}, pd[4] = {0.f, 0.f, 0.f, 0.f};
    #pragma unroll
    for (int nt = 0; nt < 4; ++nt) {
        f32x4 acc = {0.f, 0.f, 0.f, 0.f};
        #pragma unroll
        for (int ks = 0; ks < 8; ++ks) {
            bf16x8 b = *reinterpret_cast<const bf16x8*>(
                wb + (size_t)(nt * 16 + lr) * 512 + ks * 64 + lq * 16);
            acc = __builtin_amdgcn_mfma_f32_16x16x32_bf16(a[ks], b, acc, 0, 0, 0);
        }
        int col = nt * 16 + lr;
        float sa = att_s2[col], da = att_d2[col];
        #pragma unroll
        for (int reg = 0; reg < 4; ++reg) {
            int row = row0 + w * 16 + lq * 4 + reg;
            if (row < Nn) {
                unsigned pk = __builtin_amdgcn_cvt_pk_fp8_f32(acc[reg], acc[reg], 0, false);
                h2[(size_t)row * C2 + col] = (unsigned char)(pk & 0xffu);
            }
            ps[reg] = fmaf(acc[reg], sa, ps[reg]);
            pd[reg] = fmaf(acc[reg], da, pd[reg]);
        }
    }
    #pragma unroll
    for (int reg = 0; reg < 4; ++reg) {
        #pragma unroll
        for (int mk = 8; mk >= 1; mk >>= 1) {
            ps[reg] += __shfl_xor(ps[reg], mk, 64);
            pd[reg] += __shfl_xor(pd[reg], mk, 64);
        }
    }
    if (lr == 0) {
        #pragma unroll
        for (int reg = 0; reg < 4; ++reg) {
            int row = row0 + w * 16 + lq * 4 + reg;
            if (row < Nn) { as2[row] = ps[reg]; ad2[row] = pd[reg]; }
        }
    }
}

// Layer-2 aggregation + bias + log_softmax. 1 node per 64-thread block.
__global__ __launch_bounds__(64) void agg2_kernel(
    const int* __restrict__ rowptr, const int* __restrict__ colb,
    const float* __restrict__ as2, const float* __restrict__ ad2,
    const unsigned char* __restrict__ h2, const float* __restrict__ b2,
    float* __restrict__ out, int N) {
    int lane = threadIdx.x;
    int n = blockIdx.x;
    __shared__ float sp2[64];
    __shared__ int soff2[64];
    int start = rowptr[n], end = rowptr[n + 1];
    int q = lane >> 4, l4 = lane & 15;
    soff2[lane] = 0;
    float adn = ad2[n];
    float m = -INFINITY, denom = 0.f;
    floatx2 A01 = {0.f, 0.f}, A23 = {0.f, 0.f};
    for (int base = start; base < end; base += 64) {
        int cn = min(64, end - base);
        float logit = -INFINITY;
        if (lane < cn) {
            int s = colb[base + lane];
            soff2[lane] = s << 6;
            float e = as2[s] + adn;
            logit = e > 0.f ? e : 0.2f * e;
        }
        float cmax = logit;
        #pragma unroll
        for (int mk = 32; mk >= 1; mk >>= 1) cmax = fmaxf(cmax, __shfl_xor(cmax, mk, 64));
        float newm = fmaxf(m, cmax);
        float scale = __expf(m - newm);
        floatx2 s2 = {scale, scale};
        A01 *= s2; A23 *= s2;
        denom *= scale; m = newm;
        float p = (lane < cn) ? __expf(logit - m) : 0.f;
        sp2[lane] = p;
        float psum = p;
        #pragma unroll
        for (int mk = 32; mk >= 1; mk >>= 1) psum += __shfl_xor(psum, mk, 64);
        denom += psum;
        #pragma unroll 2
        for (int e2 = 0; e2 < cn; e2 += 4) {
            int e = e2 + q;
            bool ok = e < cn;
            int off = soff2[ok ? e : 0];
            float pe = ok ? sp2[e] : 0.f;
            floatx2 p2 = {pe, pe};
            unsigned u = *reinterpret_cast<const unsigned*>(h2 + off + l4 * 4);
            floatx2 f01 = __builtin_amdgcn_cvt_pk_f32_fp8((int)u, false);
            floatx2 f23 = __builtin_amdgcn_cvt_pk_f32_fp8((int)u, true);
            A01 = __builtin_elementwise_fma(p2, f01, A01);
            A23 = __builtin_elementwise_fma(p2, f23, A23);
        }
    }
    float a0 = A01.x, a1 = A01.y, a2 = A23.x, a3 = A23.y;
    a0 += __shfl_xor(a0, 16, 64); a1 += __shfl_xor(a1, 16, 64);
    a2 += __shfl_xor(a2, 16, 64); a3 += __shfl_xor(a3, 16, 64);
    a0 += __shfl_xor(a0, 32, 64); a1 += __shfl_xor(a1, 32, 64);
    a2 += __shfl_xor(a2, 32, 64); a3 += __shfl_xor(a3, 32, 64);
    float invd = 1.f / denom;
    const float4* bp = reinterpret_cast<const float4*>(b2 + l4 * 4);
    float4 bv = bp[0];
    float v0 = a0 * invd + bv.x, v1 = a1 * invd + bv.y;
    float v2 = a2 * invd + bv.z, v3 = a3 * invd + bv.w;
    float mx = fmaxf(fmaxf(v0, v1), fmaxf(v2, v3));
    #pragma unroll
    for (int mk = 8; mk >= 1; mk >>= 1) mx = fmaxf(mx, __shfl_xor(mx, mk, 64));
    float sum = __expf(v0 - mx) + __expf(v1 - mx) + __expf(v2 - mx) + __expf(v3 - mx);
    #pragma unroll
    for (int mk = 8; mk >= 1; mk >>= 1) sum += __shfl_xor(sum, mk, 64);
    float ls = logf(sum);
    if (q == 0) {
        float4 o = make_float4(v0 - mx - ls, v1 - mx - ls, v2 - mx - ls, v3 - mx - ls);
        *reinterpret_cast<float4*>(out + (size_t)n * C2 + l4 * 4) = o;
    }
}

extern "C" void kernel_launch(void* const* d_in, const int* in_sizes, int n_in,
                              void* d_out, int out_size, void* d_ws, size_t ws_size,
                              hipStream_t stream) {
    const float* x      = (const float*)d_in[0];
    const int*   ei     = (const int*)d_in[1];
    const float* W1     = (const float*)d_in[2];
    const float* att_s1 = (const float*)d_in[3];
    const float* att_d1 = (const float*)d_in[4];
    const float* b1     = (const float*)d_in[5];
    const float* W2     = (const float*)d_in[6];
    const float* att_s2 = (const float*)d_in[7];
    const float* att_d2 = (const float*)d_in[8];
    const float* b2     = (const float*)d_in[9];
    float* out = (float*)d_out;

    const int N = out_size / C2;          // 50000
    const int E = in_sizes[1] / 2;        // 1.6M
    const int ETOT = E + N;
    const int NB = (N + 255) / 256;

    char* ws = (char*)d_ws;
    size_t off = 0;
    auto alloc = [&](size_t bytes) -> void* {
        void* p = ws + off;
        off += (bytes + 255) & ~(size_t)255;
        return p;
    };
    unsigned char* h1 = (unsigned char*)alloc((size_t)N * C1);           // 12.8 MB fp8
    __hip_bfloat16* x1e = (__hip_bfloat16*)alloc((size_t)N * C1 * 2);    // 25.6 MB bf16
    unsigned short* w1t = (unsigned short*)alloc((size_t)C1 * FIN * 2);
    unsigned short* w2t = (unsigned short*)alloc((size_t)C2 * C1 * 2);
    float* as1  = (float*)alloc((size_t)N * NH * 4);
    float* ad1  = (float*)alloc((size_t)N * NH * 4);
    float* as2  = (float*)alloc((size_t)N * 4);
    float* ad2  = (float*)alloc((size_t)N * 4);
    int*   cnt    = (int*)alloc((size_t)N * 4);
    int*   rowptr = (int*)alloc((size_t)(N + 1) * 4);
    int*   pref   = (int*)alloc((size_t)N * 4);
    int*   bsum   = (int*)alloc((size_t)NB * 4);
    int*   offs   = (int*)alloc((size_t)E * 4);
    int*   colb   = (int*)alloc((size_t)ETOT * 4);
    unsigned char* h2 = h1;   // reuse after agg1 (3.2MB <= 12.8MB)

    // --- CSR build (self-loops prefilled at rank 0 via scan3) + init ---
    const int T = (E + 3) / 4;
    init_kernel<<<(N + 255) / 256, 256, 0, stream>>>(W1, W2, cnt, w1t, w2t, N);
    hist_kernel<<<(T + 255) / 256, 256, 0, stream>>>(ei, E, T, cnt, offs);
    scan1_kernel<<<NB, 256, 0, stream>>>(cnt, N, pref, bsum);
    scan2_kernel<<<1, 256, 0, stream>>>(bsum, NB);
    scan3_kernel<<<NB, 256, 0, stream>>>(pref, bsum, N, ETOT, rowptr, colb);

    // --- Layer 1 GEMM fused with scatter (independent, complementary pipes) ---
    const int GB1 = (N + 63) / 64;
    const int GSC = (T + 255) / 256;
    gemm1_scatter_fused<<<GB1 + GSC, 256, 0, stream>>>(
        x, w1t, att_s1, att_d1, h1, as1, ad1, N, GB1, ei, rowptr, offs, E, T, colb);

    agg1_kernel<<<N, 64, 0, stream>>>(rowptr, colb, as1, ad1, h1, b1, x1e, N);

    // --- Layer 2 ---
    gemm2_mfma<<<(N + 63) / 64, 256, 0, stream>>>((const unsigned short*)x1e, w2t,
                                                  att_s2, att_d2, h2, as2, ad2, N);
    agg2_kernel<<<N, 64, 0, stream>>>(rowptr, colb, as2, ad2, h2, b2, out, N);
}